// Round 1
// baseline (6820.434 us; speedup 1.0000x reference)
//
#include <hip/hip_runtime.h>
#include <hip/hip_bf16.h>
#include <math.h>

// Problem constants
#define B_   2
#define L_   2048
#define D_   2048
#define NH   32
#define NKV  8
#define HD   64
#define OP   3072          // NH*HD + 2*NKV*HD
#define QPOS 2048          // NH*HD
#define KPOS 2048          // q ends here, k starts
#define VPOS 2560          // k ends here, v starts
#define SCALE_ 0.125f      // HD^-0.5

// ---------------- GEMM (NT): C[m][n] = sum_k A[m][k] * B[n][k] ----------------
#define GBM 128
#define GBN 128
#define GBK 16
#define GPAD 4

__global__ __launch_bounds__(256)
void gemm_nt(const float* __restrict__ A, const float* __restrict__ Bm,
             float* __restrict__ C, int M, int N, int K) {
  __shared__ float As[GBK][GBM + GPAD];
  __shared__ float Bs[GBK][GBN + GPAD];
  const int t  = threadIdx.x;
  const int m0 = blockIdx.y * GBM;
  const int n0 = blockIdx.x * GBN;
  const int tx = t & 15;   // 16 thread cols
  const int ty = t >> 4;   // 16 thread rows

  float acc[8][8];
#pragma unroll
  for (int i = 0; i < 8; ++i)
#pragma unroll
    for (int j = 0; j < 8; ++j) acc[i][j] = 0.f;

  for (int k0 = 0; k0 < K; k0 += GBK) {
    // Stage A/B tiles (transposed into [k][m] layout). 512 float4 per matrix.
#pragma unroll
    for (int i = 0; i < 2; ++i) {
      int f   = t + i * 256;          // 0..511
      int row = f >> 2;               // 0..127
      int kc  = (f & 3) << 2;         // 0,4,8,12
      float4 va = *(const float4*)(A + (size_t)(m0 + row) * K + k0 + kc);
      As[kc + 0][row] = va.x; As[kc + 1][row] = va.y;
      As[kc + 2][row] = va.z; As[kc + 3][row] = va.w;
      float4 vb = *(const float4*)(Bm + (size_t)(n0 + row) * K + k0 + kc);
      Bs[kc + 0][row] = vb.x; Bs[kc + 1][row] = vb.y;
      Bs[kc + 2][row] = vb.z; Bs[kc + 3][row] = vb.w;
    }
    __syncthreads();

#pragma unroll
    for (int kk = 0; kk < GBK; ++kk) {
      float a[8], b[8];
#pragma unroll
      for (int i = 0; i < 8; ++i) a[i] = As[kk][ty * 8 + i];
#pragma unroll
      for (int j = 0; j < 8; ++j) b[j] = Bs[kk][tx * 8 + j];
#pragma unroll
      for (int i = 0; i < 8; ++i)
#pragma unroll
        for (int j = 0; j < 8; ++j) acc[i][j] += a[i] * b[j];
    }
    __syncthreads();
  }

#pragma unroll
  for (int i = 0; i < 8; ++i) {
    float* crow = C + (size_t)(m0 + ty * 8 + i) * N + n0 + tx * 8;
    *(float4*)(crow)     = make_float4(acc[i][0], acc[i][1], acc[i][2], acc[i][3]);
    *(float4*)(crow + 4) = make_float4(acc[i][4], acc[i][5], acc[i][6], acc[i][7]);
  }
}

// ---------------- RoPE cos/sin tables: [L][32] each ----------------
__global__ void rope_tables(float* __restrict__ ctab, float* __restrict__ stab) {
  int idx = blockIdx.x * 256 + threadIdx.x;   // 0 .. L_*32-1
  if (idx >= L_ * 32) return;
  int l = idx >> 5;
  int i = idx & 31;
  float freq = powf(10000.0f, -(float)(2 * i) / 64.0f);
  float ang  = (float)l * freq;
  ctab[idx] = cosf(ang);
  stab[idx] = sinf(ang);
}

// ---------------- Flash attention (fp32, causal, GQA) ----------------
// One block per (q-tile of 64 rows, head, batch). 256 threads:
// thread t -> row r = t>>2 (0..63), col-group cg = t&3.
// S cols per thread: c = 4*j + cg  (interleaved so K-row LDS reads are
// conflict-free: for fixed j the 4 cg lanes hit 4 consecutive rows).
#define LDK 68

__global__ __launch_bounds__(256)
void attn_fwd(const float* __restrict__ qkv, const float* __restrict__ ctab,
              const float* __restrict__ stab, float* __restrict__ out) {
  __shared__ float Qs[64][LDK];
  __shared__ float Ks[64][LDK];
  __shared__ float Vs[64][LDK];

  const int t   = threadIdx.x;
  const int qt  = blockIdx.x;     // q tile 0..31
  const int h   = blockIdx.y;     // head 0..31
  const int b   = blockIdx.z;     // batch 0..1
  const int r   = t >> 2;
  const int cg  = t & 3;
  const int kvh = h >> 2;         // rep = 4
  const float* base = qkv + (size_t)b * L_ * OP;
  const int qoff = h * HD;
  const int koff = KPOS + kvh * HD;
  const int voff = VPOS + kvh * HD;
  const int ql   = qt * 64 + r;   // this thread's global q row

  // ---- load Q tile raw ----
  {
    const float* src = base + (size_t)ql * OP + qoff + cg * 16;
#pragma unroll
    for (int u = 0; u < 4; ++u) {
      float4 v = *(const float4*)(src + u * 4);
      Qs[r][cg * 16 + u * 4 + 0] = v.x; Qs[r][cg * 16 + u * 4 + 1] = v.y;
      Qs[r][cg * 16 + u * 4 + 2] = v.z; Qs[r][cg * 16 + u * 4 + 3] = v.w;
    }
  }
  __syncthreads();
  // ---- RoPE(Q) * SCALE, in place ----
  {
    float tmp[16];
    const float* cr = ctab + (size_t)ql * 32;
    const float* sr = stab + (size_t)ql * 32;
#pragma unroll
    for (int u = 0; u < 16; ++u) {
      int d = cg * 16 + u;
      float v;
      if (d < 32) v = Qs[r][d] * cr[d]      - Qs[r][d + 32] * sr[d];
      else        v = Qs[r][d] * cr[d - 32] + Qs[r][d - 32] * sr[d - 32];
      tmp[u] = v * SCALE_;
    }
    __syncthreads();
#pragma unroll
    for (int u = 0; u < 16; ++u) Qs[r][cg * 16 + u] = tmp[u];
  }
  __syncthreads();

  float m_run = -__builtin_inff();
  float l_run = 0.f;
  float o[16];
#pragma unroll
  for (int u = 0; u < 16; ++u) o[u] = 0.f;

  for (int kt = 0; kt <= qt; ++kt) {
    const int kl = kt * 64 + r;
    // ---- stage K (raw) + V ----
    {
      const float* ksrc = base + (size_t)kl * OP + koff + cg * 16;
      const float* vsrc = base + (size_t)kl * OP + voff + cg * 16;
#pragma unroll
      for (int u = 0; u < 4; ++u) {
        float4 k4 = *(const float4*)(ksrc + u * 4);
        Ks[r][cg * 16 + u * 4 + 0] = k4.x; Ks[r][cg * 16 + u * 4 + 1] = k4.y;
        Ks[r][cg * 16 + u * 4 + 2] = k4.z; Ks[r][cg * 16 + u * 4 + 3] = k4.w;
        float4 v4 = *(const float4*)(vsrc + u * 4);
        Vs[r][cg * 16 + u * 4 + 0] = v4.x; Vs[r][cg * 16 + u * 4 + 1] = v4.y;
        Vs[r][cg * 16 + u * 4 + 2] = v4.z; Vs[r][cg * 16 + u * 4 + 3] = v4.w;
      }
    }
    __syncthreads();
    // ---- RoPE(K) in place ----
    {
      float tmp[16];
      const float* cr = ctab + (size_t)kl * 32;
      const float* sr = stab + (size_t)kl * 32;
#pragma unroll
      for (int u = 0; u < 16; ++u) {
        int d = cg * 16 + u;
        if (d < 32) tmp[u] = Ks[r][d] * cr[d]      - Ks[r][d + 32] * sr[d];
        else        tmp[u] = Ks[r][d] * cr[d - 32] + Ks[r][d - 32] * sr[d - 32];
      }
      __syncthreads();
#pragma unroll
      for (int u = 0; u < 16; ++u) Ks[r][cg * 16 + u] = tmp[u];
    }
    __syncthreads();

    // ---- S = Q K^T for 16 cols: c = 4*j + cg ----
    float sv[16];
#pragma unroll
    for (int j = 0; j < 16; ++j) sv[j] = 0.f;
#pragma unroll
    for (int d0 = 0; d0 < 64; d0 += 16) {
      float q[16];
#pragma unroll
      for (int u = 0; u < 16; ++u) q[u] = Qs[r][d0 + u];
#pragma unroll
      for (int j = 0; j < 16; ++j) {
        const float* krow = &Ks[4 * j + cg][d0];
#pragma unroll
        for (int u = 0; u < 16; ++u) sv[j] += q[u] * krow[u];
      }
    }

    // ---- causal mask ----
#pragma unroll
    for (int j = 0; j < 16; ++j) {
      int cglob = kt * 64 + 4 * j + cg;
      if (cglob > ql) sv[j] = -__builtin_inff();
    }

    // ---- online softmax (row = 4 adjacent lanes) ----
    float mloc = sv[0];
#pragma unroll
    for (int j = 1; j < 16; ++j) mloc = fmaxf(mloc, sv[j]);
    mloc = fmaxf(mloc, __shfl_xor(mloc, 1));
    mloc = fmaxf(mloc, __shfl_xor(mloc, 2));
    float mnew  = fmaxf(m_run, mloc);
    float alpha = __expf(m_run - mnew);
    float psum  = 0.f;
#pragma unroll
    for (int j = 0; j < 16; ++j) {
      float p = __expf(sv[j] - mnew);
      sv[j] = p;
      psum += p;
    }
    psum += __shfl_xor(psum, 1);
    psum += __shfl_xor(psum, 2);
    l_run = l_run * alpha + psum;
    m_run = mnew;
#pragma unroll
    for (int u = 0; u < 16; ++u) o[u] *= alpha;

    // ---- O += P * V ; P[r][c] lives in lane ((t&~3)|(c&3)), reg c>>2 ----
#pragma unroll
    for (int c = 0; c < 64; ++c) {
      float pc = __shfl(sv[c >> 2], ((t & 63) & ~3) | (c & 3));
      const float* vrow = &Vs[c][cg * 16];
#pragma unroll
      for (int dd = 0; dd < 16; ++dd) o[dd] += pc * vrow[dd];
    }
    __syncthreads();   // before next tile overwrites Ks/Vs
  }

  // ---- normalize + store ----
  float inv = 1.f / l_run;
  float* dst = out + ((size_t)(b * L_ + ql)) * QPOS + h * HD + cg * 16;
#pragma unroll
  for (int u = 0; u < 4; ++u) {
    *(float4*)(dst + u * 4) = make_float4(o[u * 4 + 0] * inv, o[u * 4 + 1] * inv,
                                          o[u * 4 + 2] * inv, o[u * 4 + 3] * inv);
  }
}

// ---------------- launch ----------------
extern "C" void kernel_launch(void* const* d_in, const int* in_sizes, int n_in,
                              void* d_out, int out_size, void* d_ws, size_t ws_size,
                              hipStream_t stream) {
  const float* x    = (const float*)d_in[0];   // [B,L,D]
  const float* Wqkv = (const float*)d_in[1];   // [OP,D]
  const float* Wo   = (const float*)d_in[2];   // [D, NH*HD]
  float* outp = (float*)d_out;                 // [B,L,D]
  float* ws   = (float*)d_ws;

  float* qkv_ws  = ws;                                   // 4096*3072
  float* attn_ws = qkv_ws + (size_t)(B_ * L_) * OP;      // 4096*2048
  float* ctab    = attn_ws + (size_t)(B_ * L_) * QPOS;   // 65536
  float* stab    = ctab + (size_t)L_ * 32;               // 65536

  // 1) QKV projection: qkv[m][o] = sum_d x[m][d] * Wqkv[o][d]
  dim3 g1(OP / GBN, (B_ * L_) / GBM);
  gemm_nt<<<g1, 256, 0, stream>>>(x, Wqkv, qkv_ws, B_ * L_, OP, D_);

  // 2) RoPE tables
  rope_tables<<<dim3((L_ * 32 + 255) / 256), 256, 0, stream>>>(ctab, stab);

  // 3) attention
  dim3 ga(L_ / 64, NH, B_);
  attn_fwd<<<ga, 256, 0, stream>>>(qkv_ws, ctab, stab, attn_ws);

  // 4) output projection: out[m][d] = sum_h attn[m][h] * Wo[d][h]
  dim3 g2(D_ / GBN, (B_ * L_) / GBM);
  gemm_nt<<<g2, 256, 0, stream>>>(attn_ws, Wo, outp, B_ * L_, D_, QPOS);
}

// Round 2
// 2066.907 us; speedup vs baseline: 3.2998x; 3.2998x over previous
//
#include <hip/hip_runtime.h>
#include <hip/hip_bf16.h>
#include <math.h>

// Problem constants
#define B_   2
#define L_   2048
#define D_   2048
#define NH   32
#define NKV  8
#define HD   64
#define OP   3072          // NH*HD + 2*NKV*HD
#define QPOS 2048          // NH*HD
#define KPOS 2048          // q ends here, k starts
#define VPOS 2560          // k ends here, v starts
#define SCALE_ 0.125f      // HD^-0.5
#define NEG_BIG -1.0e30f

// ---------------- GEMM (NT): C[m][n] = sum_k A[m][k] * B[n][k] ----------------
#define GBM 128
#define GBN 128
#define GBK 16
#define GPAD 4

__global__ __launch_bounds__(256)
void gemm_nt(const float* __restrict__ A, const float* __restrict__ Bm,
             float* __restrict__ C, int M, int N, int K) {
  __shared__ float As[GBK][GBM + GPAD];
  __shared__ float Bs[GBK][GBN + GPAD];
  const int t  = threadIdx.x;
  const int m0 = blockIdx.y * GBM;
  const int n0 = blockIdx.x * GBN;
  const int tx = t & 15;
  const int ty = t >> 4;

  float acc[8][8];
#pragma unroll
  for (int i = 0; i < 8; ++i)
#pragma unroll
    for (int j = 0; j < 8; ++j) acc[i][j] = 0.f;

  for (int k0 = 0; k0 < K; k0 += GBK) {
#pragma unroll
    for (int i = 0; i < 2; ++i) {
      int f   = t + i * 256;
      int row = f >> 2;
      int kc  = (f & 3) << 2;
      float4 va = *(const float4*)(A + (size_t)(m0 + row) * K + k0 + kc);
      As[kc + 0][row] = va.x; As[kc + 1][row] = va.y;
      As[kc + 2][row] = va.z; As[kc + 3][row] = va.w;
      float4 vb = *(const float4*)(Bm + (size_t)(n0 + row) * K + k0 + kc);
      Bs[kc + 0][row] = vb.x; Bs[kc + 1][row] = vb.y;
      Bs[kc + 2][row] = vb.z; Bs[kc + 3][row] = vb.w;
    }
    __syncthreads();

#pragma unroll
    for (int kk = 0; kk < GBK; ++kk) {
      float a[8], b[8];
#pragma unroll
      for (int i = 0; i < 8; ++i) a[i] = As[kk][ty * 8 + i];
#pragma unroll
      for (int j = 0; j < 8; ++j) b[j] = Bs[kk][tx * 8 + j];
#pragma unroll
      for (int i = 0; i < 8; ++i)
#pragma unroll
        for (int j = 0; j < 8; ++j) acc[i][j] += a[i] * b[j];
    }
    __syncthreads();
  }

#pragma unroll
  for (int i = 0; i < 8; ++i) {
    float* crow = C + (size_t)(m0 + ty * 8 + i) * N + n0 + tx * 8;
    *(float4*)(crow)     = make_float4(acc[i][0], acc[i][1], acc[i][2], acc[i][3]);
    *(float4*)(crow + 4) = make_float4(acc[i][4], acc[i][5], acc[i][6], acc[i][7]);
  }
}

// ---------------- RoPE cos/sin tables: [L][32] each ----------------
__global__ void rope_tables(float* __restrict__ ctab, float* __restrict__ stab) {
  int idx = blockIdx.x * 256 + threadIdx.x;
  if (idx >= L_ * 32) return;
  int l = idx >> 5;
  int i = idx & 31;
  float freq = powf(10000.0f, -(float)(2 * i) / 64.0f);
  float ang  = (float)l * freq;
  ctab[idx] = cosf(ang);
  stab[idx] = sinf(ang);
}

// ---------------- RoPE applied in place to Q (with scale) and K slices -------
// One block per (b,l) row; 40 heads x 32 rot-pairs = 1280 items, 5 per thread.
__global__ __launch_bounds__(256)
void rope_inplace(float* __restrict__ qkv, const float* __restrict__ ctab,
                  const float* __restrict__ stab) {
  const int row = blockIdx.x;            // b*L + l
  const int l   = row & (L_ - 1);
  float* p = qkv + (size_t)row * OP;
  const int t = threadIdx.x;
#pragma unroll
  for (int k = 0; k < 5; ++k) {
    int item = t + k * 256;              // 0..1279
    int hh = item >> 5;                  // 0..39
    int d  = item & 31;
    int off = (hh < NH) ? hh * HD + d : KPOS + (hh - NH) * HD + d;
    float sc = (hh < NH) ? SCALE_ : 1.0f;
    float c = ctab[l * 32 + d];
    float s = stab[l * 32 + d];
    float a = p[off];
    float bq = p[off + 32];
    p[off]      = (a * c - bq * s) * sc;
    p[off + 32] = (bq * c + a * s) * sc;
  }
}

// ---------------- Flash attention, GEMM-structured (fp32, causal, GQA) -------
// Block = (q-tile 64 rows, head, batch), 256 threads as 16x16 grid.
// Thread (ty,tx): S rows ty*4+{0..3}, S cols tx*4+{0..3}; 4x4 microtile.
// Q,K staged TRANSPOSED (QsT[d][l]) so both GEMM operands are ds_read_b128:
//   A-read QsT[d][ty*4] : 4 distinct 16B lines, broadcast across tx -> free
//   B-read KsT[d][tx*4] : 64 consecutive words -> 2-way alias -> free
// P staged transposed (SsT[col][row]) so PV A-operand is also b128.
#define LDA 68   // 272B row stride: 16B-aligned for b128

__global__ __launch_bounds__(256)
void attn_fwd2(const float* __restrict__ qkv, float* __restrict__ out) {
  __shared__ float QsT[HD][LDA];
  __shared__ float KsT[HD][LDA];
  __shared__ float Vs[64][LDA];
  __shared__ float SsT[64][LDA];

  const int t   = threadIdx.x;
  const int qt  = blockIdx.x;
  const int h   = blockIdx.y;
  const int b   = blockIdx.z;
  const int kvh = h >> 2;                // rep = 4
  const int tx  = t & 15;
  const int ty  = t >> 4;
  const int r   = t >> 2;                // staging row 0..63
  const int seg = t & 3;                 // staging 16-float segment
  const float* base = qkv + (size_t)b * L_ * OP;

  // ---- stage Q transposed (once) ----
  {
    const float* src = base + (size_t)(qt * 64 + r) * OP + h * HD + seg * 16;
#pragma unroll
    for (int u = 0; u < 4; ++u) {
      float4 v = *(const float4*)(src + 4 * u);
      int d = seg * 16 + 4 * u;
      QsT[d + 0][r] = v.x; QsT[d + 1][r] = v.y;
      QsT[d + 2][r] = v.z; QsT[d + 3][r] = v.w;
    }
  }

  float m_run[4], l_run[4], o[4][4];
#pragma unroll
  for (int i = 0; i < 4; ++i) {
    m_run[i] = NEG_BIG; l_run[i] = 0.f;
#pragma unroll
    for (int j = 0; j < 4; ++j) o[i][j] = 0.f;
  }

  for (int kt = 0; kt <= qt; ++kt) {
    // ---- stage K transposed + V row-major ----
    {
      const float* ksrc = base + (size_t)(kt * 64 + r) * OP + KPOS + kvh * HD + seg * 16;
      const float* vsrc = base + (size_t)(kt * 64 + r) * OP + VPOS + kvh * HD + seg * 16;
#pragma unroll
      for (int u = 0; u < 4; ++u) {
        float4 kv = *(const float4*)(ksrc + 4 * u);
        int d = seg * 16 + 4 * u;
        KsT[d + 0][r] = kv.x; KsT[d + 1][r] = kv.y;
        KsT[d + 2][r] = kv.z; KsT[d + 3][r] = kv.w;
        *(float4*)&Vs[r][seg * 16 + 4 * u] = *(const float4*)(vsrc + 4 * u);
      }
    }
    __syncthreads();   // covers Q staging on first iter too

    // ---- S = Q K^T (4x4 microtile) ----
    float s4[4][4];
#pragma unroll
    for (int i = 0; i < 4; ++i)
#pragma unroll
      for (int j = 0; j < 4; ++j) s4[i][j] = 0.f;

#pragma unroll 4
    for (int d = 0; d < 64; ++d) {
      float4 qa = *(const float4*)&QsT[d][ty * 4];
      float4 kb = *(const float4*)&KsT[d][tx * 4];
      float a[4] = {qa.x, qa.y, qa.z, qa.w};
      float bb[4] = {kb.x, kb.y, kb.z, kb.w};
#pragma unroll
      for (int i = 0; i < 4; ++i)
#pragma unroll
        for (int j = 0; j < 4; ++j) s4[i][j] += a[i] * bb[j];
    }

    // ---- causal mask (only the diagonal tile) ----
    if (kt == qt) {
#pragma unroll
      for (int i = 0; i < 4; ++i)
#pragma unroll
        for (int j = 0; j < 4; ++j)
          if (tx * 4 + j > ty * 4 + i) s4[i][j] = NEG_BIG;
    }

    // ---- online softmax; row = 16 lanes sharing ty ----
#pragma unroll
    for (int i = 0; i < 4; ++i) {
      float mloc = fmaxf(fmaxf(s4[i][0], s4[i][1]), fmaxf(s4[i][2], s4[i][3]));
      mloc = fmaxf(mloc, __shfl_xor(mloc, 1));
      mloc = fmaxf(mloc, __shfl_xor(mloc, 2));
      mloc = fmaxf(mloc, __shfl_xor(mloc, 4));
      mloc = fmaxf(mloc, __shfl_xor(mloc, 8));
      float mnew  = fmaxf(m_run[i], mloc);
      float alpha = __expf(m_run[i] - mnew);
      float psum  = 0.f;
#pragma unroll
      for (int j = 0; j < 4; ++j) {
        float pv = __expf(s4[i][j] - mnew);
        s4[i][j] = pv;
        psum += pv;
      }
      psum += __shfl_xor(psum, 1);
      psum += __shfl_xor(psum, 2);
      psum += __shfl_xor(psum, 4);
      psum += __shfl_xor(psum, 8);
      l_run[i] = l_run[i] * alpha + psum;
      m_run[i] = mnew;
#pragma unroll
      for (int j = 0; j < 4; ++j) o[i][j] *= alpha;
    }

    // ---- store P transposed: SsT[col][row] ----
#pragma unroll
    for (int j = 0; j < 4; ++j)
#pragma unroll
      for (int i = 0; i < 4; ++i)
        SsT[tx * 4 + j][ty * 4 + i] = s4[i][j];
    __syncthreads();

    // ---- O += P V (4x4 microtile over k) ----
#pragma unroll 4
    for (int k = 0; k < 64; ++k) {
      float4 pa = *(const float4*)&SsT[k][ty * 4];
      float4 vb = *(const float4*)&Vs[k][tx * 4];
      float a[4] = {pa.x, pa.y, pa.z, pa.w};
      float bb[4] = {vb.x, vb.y, vb.z, vb.w};
#pragma unroll
      for (int i = 0; i < 4; ++i)
#pragma unroll
        for (int j = 0; j < 4; ++j) o[i][j] += a[i] * bb[j];
    }
    __syncthreads();   // before next tile overwrites KsT/Vs/SsT
  }

  // ---- normalize + store ----
#pragma unroll
  for (int i = 0; i < 4; ++i) {
    float inv = 1.f / l_run[i];
    float* dst = out + ((size_t)(b * L_ + qt * 64 + ty * 4 + i)) * QPOS + h * HD + tx * 4;
    *(float4*)dst = make_float4(o[i][0] * inv, o[i][1] * inv,
                                o[i][2] * inv, o[i][3] * inv);
  }
}

// ---------------- launch ----------------
extern "C" void kernel_launch(void* const* d_in, const int* in_sizes, int n_in,
                              void* d_out, int out_size, void* d_ws, size_t ws_size,
                              hipStream_t stream) {
  const float* x    = (const float*)d_in[0];   // [B,L,D]
  const float* Wqkv = (const float*)d_in[1];   // [OP,D]
  const float* Wo   = (const float*)d_in[2];   // [D, NH*HD]
  float* outp = (float*)d_out;                 // [B,L,D]
  float* ws   = (float*)d_ws;

  float* qkv_ws  = ws;                                   // 4096*3072
  float* attn_ws = qkv_ws + (size_t)(B_ * L_) * OP;      // 4096*2048
  float* ctab    = attn_ws + (size_t)(B_ * L_) * QPOS;   // 65536
  float* stab    = ctab + (size_t)L_ * 32;               // 65536

  // 1) QKV projection
  dim3 g1(OP / GBN, (B_ * L_) / GBM);
  gemm_nt<<<g1, 256, 0, stream>>>(x, Wqkv, qkv_ws, B_ * L_, OP, D_);

  // 2) RoPE tables + in-place RoPE on Q (scaled) and K
  rope_tables<<<dim3((L_ * 32 + 255) / 256), 256, 0, stream>>>(ctab, stab);
  rope_inplace<<<dim3(B_ * L_), 256, 0, stream>>>(qkv_ws, ctab, stab);

  // 3) attention
  dim3 ga(L_ / 64, NH, B_);
  attn_fwd2<<<ga, 256, 0, stream>>>(qkv_ws, attn_ws);

  // 4) output projection
  dim3 g2(D_ / GBN, (B_ * L_) / GBM);
  gemm_nt<<<g2, 256, 0, stream>>>(attn_ws, Wo, outp, B_ * L_, D_, QPOS);
}

// Round 3
// 1504.589 us; speedup vs baseline: 4.5331x; 1.3737x over previous
//
#include <hip/hip_runtime.h>
#include <math.h>

// Problem constants
#define B_   2
#define L_   2048
#define D_   2048
#define NH   32
#define NKV  8
#define HD   64
#define OP   3072          // NH*HD + 2*NKV*HD
#define QPOS 2048
#define KPOS 2048
#define VPOS 2560
#define SCALE_ 0.125f
#define NEG_BIG -1.0e30f

typedef __attribute__((ext_vector_type(8))) short s16x8;   // 8 bf16 in 4 VGPRs
typedef __attribute__((ext_vector_type(4))) float f32x4;

// ---- bf16 helpers (bit-level, header-independent) ----
__device__ __forceinline__ unsigned short f2bf(float f) {
  unsigned int u = __float_as_uint(f);
  u += 0x7fffu + ((u >> 16) & 1u);         // round-to-nearest-even
  return (unsigned short)(u >> 16);
}
__device__ __forceinline__ float bf2f(unsigned short h) {
  return __uint_as_float((unsigned int)h << 16);
}

// ---- async global->LDS, 16B per lane ----
__device__ __forceinline__ void gload16(const unsigned short* g, unsigned short* l) {
  __builtin_amdgcn_global_load_lds(
      (const __attribute__((address_space(1))) unsigned int*)g,
      (__attribute__((address_space(3))) unsigned int*)l, 16, 0, 0);
}

// =================== split: fp32 [R][K] -> bf16 [R][3K] ===================
// mode 0 (A-side): [hi | lo | hi]    mode 1 (B-side): [hi | hi | lo]
// One block per row; 256 threads x 8 elems covers K=2048.
__global__ __launch_bounds__(256)
void split3(const float* __restrict__ src, unsigned short* __restrict__ dst,
            int K, int mode) {
  const int r = blockIdx.x;
  const int c = threadIdx.x * 8;
  const float* s = src + (size_t)r * K + c;
  float4 v0 = *(const float4*)s;
  float4 v1 = *(const float4*)(s + 4);
  float v[8] = {v0.x, v0.y, v0.z, v0.w, v1.x, v1.y, v1.z, v1.w};
  unsigned short hi[8], lo[8];
#pragma unroll
  for (int j = 0; j < 8; ++j) {
    hi[j] = f2bf(v[j]);
    lo[j] = f2bf(v[j] - bf2f(hi[j]));
  }
  unsigned short* d = dst + (size_t)r * 3 * K;
  s16x8 hv, lv;
#pragma unroll
  for (int j = 0; j < 8; ++j) { hv[j] = (short)hi[j]; lv[j] = (short)lo[j]; }
  *(s16x8*)(d + c)         = hv;
  *(s16x8*)(d + K + c)     = (mode == 0) ? lv : hv;
  *(s16x8*)(d + 2 * K + c) = (mode == 0) ? hv : lv;
}

// =================== bf16 NT GEMM (m97 structure) ===================
// C[m][n] = sum_k A2[m][k] * B2[n][k], K2 = 3K. 128x128 tile, BK=64.
// 4 waves in 2x2 grid of 64x64; per wave 4x4 fragments of 16x16x32 MFMA.
#define TBM 128
#define TBN 128
#define TBK 64

__global__ __launch_bounds__(256)
void gemm_bt_bf16(const unsigned short* __restrict__ A2,
                  const unsigned short* __restrict__ B2,
                  float* __restrict__ C, int M, int N, int K2) {
  __shared__ unsigned short As[TBM * TBK];   // [128][64] row-major, linear
  __shared__ unsigned short Bs[TBN * TBK];

  const int t  = threadIdx.x;
  const int m0 = blockIdx.y * TBM;
  const int n0 = blockIdx.x * TBN;
  const int w  = t >> 6;
  const int l  = t & 63;
  const int wr = (w >> 1) * 64;   // wave row offset in tile
  const int wc = (w & 1) * 64;    // wave col offset in tile

  // staging map: instr i covers rows i*32 + t/8, col (t&7)*8 (16B per lane)
  const int srow = t >> 3;
  const int scol = (t & 7) * 8;

  f32x4 acc[4][4];
#pragma unroll
  for (int m = 0; m < 4; ++m)
#pragma unroll
    for (int n = 0; n < 4; ++n)
#pragma unroll
      for (int q = 0; q < 4; ++q) acc[m][n][q] = 0.f;

  const int nsteps = K2 / TBK;
  for (int ks = 0; ks < nsteps; ++ks) {
    const size_t kb = (size_t)ks * TBK;
#pragma unroll
    for (int i = 0; i < 4; ++i) {
      int row = i * 32 + srow;
      gload16(A2 + (size_t)(m0 + row) * K2 + kb + scol, &As[row * TBK + scol]);
      gload16(B2 + (size_t)(n0 + row) * K2 + kb + scol, &Bs[row * TBK + scol]);
    }
    __syncthreads();   // drains vmcnt for global_load_lds + barrier

#pragma unroll
    for (int kk = 0; kk < 2; ++kk) {
      s16x8 af[4], bf[4];
      const int ko = kk * 32 + (l >> 4) * 8;
#pragma unroll
      for (int m = 0; m < 4; ++m)
        af[m] = *(const s16x8*)&As[(wr + m * 16 + (l & 15)) * TBK + ko];
#pragma unroll
      for (int n = 0; n < 4; ++n)
        bf[n] = *(const s16x8*)&Bs[(wc + n * 16 + (l & 15)) * TBK + ko];
#pragma unroll
      for (int m = 0; m < 4; ++m)
#pragma unroll
        for (int n = 0; n < 4; ++n)
          acc[m][n] = __builtin_amdgcn_mfma_f32_16x16x32_bf16(af[m], bf[n], acc[m][n], 0, 0, 0);
    }
    __syncthreads();   // before next stage overwrites As/Bs
  }

  // C/D layout: col = lane&15, row = (lane>>4)*4 + reg   [m89 verified]
#pragma unroll
  for (int m = 0; m < 4; ++m)
#pragma unroll
    for (int n = 0; n < 4; ++n) {
      int gr = m0 + wr + m * 16 + (l >> 4) * 4;
      int gc = n0 + wc + n * 16 + (l & 15);
#pragma unroll
      for (int j = 0; j < 4; ++j)
        C[(size_t)(gr + j) * N + gc] = acc[m][n][j];
    }
}

// =================== fp32 GEMM fallback (unchanged from round 2) ===========
#define GBM 128
#define GBN 128
#define GBK 16
#define GPAD 4

__global__ __launch_bounds__(256)
void gemm_nt(const float* __restrict__ A, const float* __restrict__ Bm,
             float* __restrict__ C, int M, int N, int K) {
  __shared__ float Asf[GBK][GBM + GPAD];
  __shared__ float Bsf[GBK][GBN + GPAD];
  const int t  = threadIdx.x;
  const int m0 = blockIdx.y * GBM;
  const int n0 = blockIdx.x * GBN;
  const int tx = t & 15;
  const int ty = t >> 4;

  float acc[8][8];
#pragma unroll
  for (int i = 0; i < 8; ++i)
#pragma unroll
    for (int j = 0; j < 8; ++j) acc[i][j] = 0.f;

  for (int k0 = 0; k0 < K; k0 += GBK) {
#pragma unroll
    for (int i = 0; i < 2; ++i) {
      int f   = t + i * 256;
      int row = f >> 2;
      int kc  = (f & 3) << 2;
      float4 va = *(const float4*)(A + (size_t)(m0 + row) * K + k0 + kc);
      Asf[kc + 0][row] = va.x; Asf[kc + 1][row] = va.y;
      Asf[kc + 2][row] = va.z; Asf[kc + 3][row] = va.w;
      float4 vb = *(const float4*)(Bm + (size_t)(n0 + row) * K + k0 + kc);
      Bsf[kc + 0][row] = vb.x; Bsf[kc + 1][row] = vb.y;
      Bsf[kc + 2][row] = vb.z; Bsf[kc + 3][row] = vb.w;
    }
    __syncthreads();
#pragma unroll
    for (int kk = 0; kk < GBK; ++kk) {
      float a[8], b[8];
#pragma unroll
      for (int i = 0; i < 8; ++i) a[i] = Asf[kk][ty * 8 + i];
#pragma unroll
      for (int j = 0; j < 8; ++j) b[j] = Bsf[kk][tx * 8 + j];
#pragma unroll
      for (int i = 0; i < 8; ++i)
#pragma unroll
        for (int j = 0; j < 8; ++j) acc[i][j] += a[i] * b[j];
    }
    __syncthreads();
  }
#pragma unroll
  for (int i = 0; i < 8; ++i) {
    float* crow = C + (size_t)(m0 + ty * 8 + i) * N + n0 + tx * 8;
    *(float4*)(crow)     = make_float4(acc[i][0], acc[i][1], acc[i][2], acc[i][3]);
    *(float4*)(crow + 4) = make_float4(acc[i][4], acc[i][5], acc[i][6], acc[i][7]);
  }
}

// ---------------- RoPE cos/sin tables: [L][32] each ----------------
__global__ void rope_tables(float* __restrict__ ctab, float* __restrict__ stab) {
  int idx = blockIdx.x * 256 + threadIdx.x;
  if (idx >= L_ * 32) return;
  int l = idx >> 5;
  int i = idx & 31;
  float freq = powf(10000.0f, -(float)(2 * i) / 64.0f);
  float ang  = (float)l * freq;
  ctab[idx] = cosf(ang);
  stab[idx] = sinf(ang);
}

// ---------------- RoPE in place on Q (scaled) and K ----------------
__global__ __launch_bounds__(256)
void rope_inplace(float* __restrict__ qkv, const float* __restrict__ ctab,
                  const float* __restrict__ stab) {
  const int row = blockIdx.x;
  const int l   = row & (L_ - 1);
  float* p = qkv + (size_t)row * OP;
  const int t = threadIdx.x;
#pragma unroll
  for (int k = 0; k < 5; ++k) {
    int item = t + k * 256;
    int hh = item >> 5;
    int d  = item & 31;
    int off = (hh < NH) ? hh * HD + d : KPOS + (hh - NH) * HD + d;
    float sc = (hh < NH) ? SCALE_ : 1.0f;
    float c = ctab[l * 32 + d];
    float s = stab[l * 32 + d];
    float a = p[off];
    float bq = p[off + 32];
    p[off]      = (a * c - bq * s) * sc;
    p[off + 32] = (bq * c + a * s) * sc;
  }
}

// ---------------- Flash attention (unchanged from round 2) ----------------
#define LDA 68

__global__ __launch_bounds__(256)
void attn_fwd2(const float* __restrict__ qkv, float* __restrict__ out) {
  __shared__ float QsT[HD][LDA];
  __shared__ float KsT[HD][LDA];
  __shared__ float Vs[64][LDA];
  __shared__ float SsT[64][LDA];

  const int t   = threadIdx.x;
  const int qt  = blockIdx.x;
  const int h   = blockIdx.y;
  const int b   = blockIdx.z;
  const int kvh = h >> 2;
  const int tx  = t & 15;
  const int ty  = t >> 4;
  const int r   = t >> 2;
  const int seg = t & 3;
  const float* base = qkv + (size_t)b * L_ * OP;

  {
    const float* src = base + (size_t)(qt * 64 + r) * OP + h * HD + seg * 16;
#pragma unroll
    for (int u = 0; u < 4; ++u) {
      float4 v = *(const float4*)(src + 4 * u);
      int d = seg * 16 + 4 * u;
      QsT[d + 0][r] = v.x; QsT[d + 1][r] = v.y;
      QsT[d + 2][r] = v.z; QsT[d + 3][r] = v.w;
    }
  }

  float m_run[4], l_run[4], o[4][4];
#pragma unroll
  for (int i = 0; i < 4; ++i) {
    m_run[i] = NEG_BIG; l_run[i] = 0.f;
#pragma unroll
    for (int j = 0; j < 4; ++j) o[i][j] = 0.f;
  }

  for (int kt = 0; kt <= qt; ++kt) {
    {
      const float* ksrc = base + (size_t)(kt * 64 + r) * OP + KPOS + kvh * HD + seg * 16;
      const float* vsrc = base + (size_t)(kt * 64 + r) * OP + VPOS + kvh * HD + seg * 16;
#pragma unroll
      for (int u = 0; u < 4; ++u) {
        float4 kv = *(const float4*)(ksrc + 4 * u);
        int d = seg * 16 + 4 * u;
        KsT[d + 0][r] = kv.x; KsT[d + 1][r] = kv.y;
        KsT[d + 2][r] = kv.z; KsT[d + 3][r] = kv.w;
        *(float4*)&Vs[r][seg * 16 + 4 * u] = *(const float4*)(vsrc + 4 * u);
      }
    }
    __syncthreads();

    float s4[4][4];
#pragma unroll
    for (int i = 0; i < 4; ++i)
#pragma unroll
      for (int j = 0; j < 4; ++j) s4[i][j] = 0.f;

#pragma unroll 4
    for (int d = 0; d < 64; ++d) {
      float4 qa = *(const float4*)&QsT[d][ty * 4];
      float4 kb = *(const float4*)&KsT[d][tx * 4];
      float a[4] = {qa.x, qa.y, qa.z, qa.w};
      float bb[4] = {kb.x, kb.y, kb.z, kb.w};
#pragma unroll
      for (int i = 0; i < 4; ++i)
#pragma unroll
        for (int j = 0; j < 4; ++j) s4[i][j] += a[i] * bb[j];
    }

    if (kt == qt) {
#pragma unroll
      for (int i = 0; i < 4; ++i)
#pragma unroll
        for (int j = 0; j < 4; ++j)
          if (tx * 4 + j > ty * 4 + i) s4[i][j] = NEG_BIG;
    }

#pragma unroll
    for (int i = 0; i < 4; ++i) {
      float mloc = fmaxf(fmaxf(s4[i][0], s4[i][1]), fmaxf(s4[i][2], s4[i][3]));
      mloc = fmaxf(mloc, __shfl_xor(mloc, 1));
      mloc = fmaxf(mloc, __shfl_xor(mloc, 2));
      mloc = fmaxf(mloc, __shfl_xor(mloc, 4));
      mloc = fmaxf(mloc, __shfl_xor(mloc, 8));
      float mnew  = fmaxf(m_run[i], mloc);
      float alpha = __expf(m_run[i] - mnew);
      float psum  = 0.f;
#pragma unroll
      for (int j = 0; j < 4; ++j) {
        float pv = __expf(s4[i][j] - mnew);
        s4[i][j] = pv;
        psum += pv;
      }
      psum += __shfl_xor(psum, 1);
      psum += __shfl_xor(psum, 2);
      psum += __shfl_xor(psum, 4);
      psum += __shfl_xor(psum, 8);
      l_run[i] = l_run[i] * alpha + psum;
      m_run[i] = mnew;
#pragma unroll
      for (int j = 0; j < 4; ++j) o[i][j] *= alpha;
    }

#pragma unroll
    for (int j = 0; j < 4; ++j)
#pragma unroll
      for (int i = 0; i < 4; ++i)
        SsT[tx * 4 + j][ty * 4 + i] = s4[i][j];
    __syncthreads();

#pragma unroll 4
    for (int k = 0; k < 64; ++k) {
      float4 pa = *(const float4*)&SsT[k][ty * 4];
      float4 vb = *(const float4*)&Vs[k][tx * 4];
      float a[4] = {pa.x, pa.y, pa.z, pa.w};
      float bb[4] = {vb.x, vb.y, vb.z, vb.w};
#pragma unroll
      for (int i = 0; i < 4; ++i)
#pragma unroll
        for (int j = 0; j < 4; ++j) o[i][j] += a[i] * bb[j];
    }
    __syncthreads();
  }

#pragma unroll
  for (int i = 0; i < 4; ++i) {
    float inv = 1.f / l_run[i];
    float* dst = out + ((size_t)(b * L_ + qt * 64 + ty * 4 + i)) * QPOS + h * HD + tx * 4;
    *(float4*)dst = make_float4(o[i][0] * inv, o[i][1] * inv,
                                o[i][2] * inv, o[i][3] * inv);
  }
}

// ---------------- launch ----------------
extern "C" void kernel_launch(void* const* d_in, const int* in_sizes, int n_in,
                              void* d_out, int out_size, void* d_ws, size_t ws_size,
                              hipStream_t stream) {
  const float* x    = (const float*)d_in[0];   // [B,L,D]
  const float* Wqkv = (const float*)d_in[1];   // [OP,D]
  const float* Wo   = (const float*)d_in[2];   // [D, NH*HD]
  float* outp = (float*)d_out;
  float* ws   = (float*)d_ws;

  float* qkv_ws  = ws;                                   // 12,582,912 f32
  float* attn_ws = qkv_ws + (size_t)(B_ * L_) * OP;      //  8,388,608 f32
  float* ctab    = attn_ws + (size_t)(B_ * L_) * QPOS;   //     65,536 f32
  float* stab    = ctab + (size_t)L_ * 32;               //     65,536 f32
  unsigned short* A2 = (unsigned short*)(stab + (size_t)L_ * 32);  // 25,165,824 u16 (x2 / attn2)
  unsigned short* B2 = A2 + (size_t)4096 * 6144;                   // 18,874,368 u16 (Wqkv2 / Wo2)

  const size_t NEED = ((size_t)21102592) * 4 + ((size_t)44040192) * 2;  // 172,490,752 B
  const bool mfma_ok = ws_size >= NEED;

  if (mfma_ok) {
    // 1) split x and Wqkv, QKV projection via bf16 MFMA (K' = 3K = 6144)
    split3<<<dim3(B_ * L_), 256, 0, stream>>>(x, A2, D_, 0);
    split3<<<dim3(OP), 256, 0, stream>>>(Wqkv, B2, D_, 1);
    gemm_bt_bf16<<<dim3(OP / TBN, (B_ * L_) / TBM), 256, 0, stream>>>(
        A2, B2, qkv_ws, B_ * L_, OP, 3 * D_);
  } else {
    gemm_nt<<<dim3(OP / GBN, (B_ * L_) / GBM), 256, 0, stream>>>(
        x, Wqkv, qkv_ws, B_ * L_, OP, D_);
  }

  // 2) RoPE
  rope_tables<<<dim3((L_ * 32 + 255) / 256), 256, 0, stream>>>(ctab, stab);
  rope_inplace<<<dim3(B_ * L_), 256, 0, stream>>>(qkv_ws, ctab, stab);

  // 3) attention (unchanged this round)
  dim3 ga(L_ / 64, NH, B_);
  attn_fwd2<<<ga, 256, 0, stream>>>(qkv_ws, attn_ws);

  // 4) output projection
  if (mfma_ok) {
    split3<<<dim3(B_ * L_), 256, 0, stream>>>(attn_ws, A2, QPOS, 0);
    split3<<<dim3(D_), 256, 0, stream>>>(Wo, B2, QPOS, 1);
    gemm_bt_bf16<<<dim3(D_ / TBN, (B_ * L_) / TBM), 256, 0, stream>>>(
        A2, B2, outp, B_ * L_, D_, 3 * QPOS);
  } else {
    gemm_nt<<<dim3(D_ / GBN, (B_ * L_) / GBM), 256, 0, stream>>>(
        attn_ws, Wo, outp, B_ * L_, D_, QPOS);
  }
}

// Round 4
// 951.642 us; speedup vs baseline: 7.1670x; 1.5810x over previous
//
#include <hip/hip_runtime.h>
#include <math.h>

// Problem constants
#define B_   2
#define L_   2048
#define D_   2048
#define NH   32
#define NKV  8
#define HD   64
#define OP   3072          // NH*HD + 2*NKV*HD
#define QPOS 2048
#define KPOS 2048
#define VPOS 2560
#define SCALE_ 0.125f
#define NEG_BIG -1.0e30f

typedef __attribute__((ext_vector_type(8))) short s16x8;   // 8 bf16 in 4 VGPRs
typedef __attribute__((ext_vector_type(4))) float f32x4;

// ---- bf16 helpers ----
__device__ __forceinline__ unsigned short f2bf(float f) {
  unsigned int u = __float_as_uint(f);
  u += 0x7fffu + ((u >> 16) & 1u);         // RNE
  return (unsigned short)(u >> 16);
}
__device__ __forceinline__ float bf2f(unsigned short h) {
  return __uint_as_float((unsigned int)h << 16);
}

// ---- async global->LDS, 16B per lane ----
__device__ __forceinline__ void gload16(const unsigned short* g, unsigned short* l) {
  __builtin_amdgcn_global_load_lds(
      (const __attribute__((address_space(1))) unsigned int*)g,
      (__attribute__((address_space(3))) unsigned int*)l, 16, 0, 0);
}

// =================== split: fp32 [R][K] -> bf16 [R][3K] ===================
__global__ __launch_bounds__(256)
void split3(const float* __restrict__ src, unsigned short* __restrict__ dst,
            int K, int mode) {
  const int r = blockIdx.x;
  const int c = threadIdx.x * 8;
  const float* s = src + (size_t)r * K + c;
  float4 v0 = *(const float4*)s;
  float4 v1 = *(const float4*)(s + 4);
  float v[8] = {v0.x, v0.y, v0.z, v0.w, v1.x, v1.y, v1.z, v1.w};
  unsigned short hi[8], lo[8];
#pragma unroll
  for (int j = 0; j < 8; ++j) {
    hi[j] = f2bf(v[j]);
    lo[j] = f2bf(v[j] - bf2f(hi[j]));
  }
  unsigned short* d = dst + (size_t)r * 3 * K;
  s16x8 hv, lv;
#pragma unroll
  for (int j = 0; j < 8; ++j) { hv[j] = (short)hi[j]; lv[j] = (short)lo[j]; }
  *(s16x8*)(d + c)         = hv;
  *(s16x8*)(d + K + c)     = (mode == 0) ? lv : hv;
  *(s16x8*)(d + 2 * K + c) = (mode == 0) ? hv : lv;
}

// =================== bf16 NT GEMM (m97 structure, unchanged) ===============
#define TBM 128
#define TBN 128
#define TBK 64

__global__ __launch_bounds__(256)
void gemm_bt_bf16(const unsigned short* __restrict__ A2,
                  const unsigned short* __restrict__ B2,
                  float* __restrict__ C, int M, int N, int K2) {
  __shared__ unsigned short As[TBM * TBK];
  __shared__ unsigned short Bs[TBN * TBK];

  const int t  = threadIdx.x;
  const int m0 = blockIdx.y * TBM;
  const int n0 = blockIdx.x * TBN;
  const int w  = t >> 6;
  const int l  = t & 63;
  const int wr = (w >> 1) * 64;
  const int wc = (w & 1) * 64;
  const int srow = t >> 3;
  const int scol = (t & 7) * 8;

  f32x4 acc[4][4];
#pragma unroll
  for (int m = 0; m < 4; ++m)
#pragma unroll
    for (int n = 0; n < 4; ++n)
#pragma unroll
      for (int q = 0; q < 4; ++q) acc[m][n][q] = 0.f;

  const int nsteps = K2 / TBK;
  for (int ks = 0; ks < nsteps; ++ks) {
    const size_t kb = (size_t)ks * TBK;
#pragma unroll
    for (int i = 0; i < 4; ++i) {
      int row = i * 32 + srow;
      gload16(A2 + (size_t)(m0 + row) * K2 + kb + scol, &As[row * TBK + scol]);
      gload16(B2 + (size_t)(n0 + row) * K2 + kb + scol, &Bs[row * TBK + scol]);
    }
    __syncthreads();

#pragma unroll
    for (int kk = 0; kk < 2; ++kk) {
      s16x8 af[4], bf[4];
      const int ko = kk * 32 + (l >> 4) * 8;
#pragma unroll
      for (int m = 0; m < 4; ++m)
        af[m] = *(const s16x8*)&As[(wr + m * 16 + (l & 15)) * TBK + ko];
#pragma unroll
      for (int n = 0; n < 4; ++n)
        bf[n] = *(const s16x8*)&Bs[(wc + n * 16 + (l & 15)) * TBK + ko];
#pragma unroll
      for (int m = 0; m < 4; ++m)
#pragma unroll
        for (int n = 0; n < 4; ++n)
          acc[m][n] = __builtin_amdgcn_mfma_f32_16x16x32_bf16(af[m], bf[n], acc[m][n], 0, 0, 0);
    }
    __syncthreads();
  }

#pragma unroll
  for (int m = 0; m < 4; ++m)
#pragma unroll
    for (int n = 0; n < 4; ++n) {
      int gr = m0 + wr + m * 16 + (l >> 4) * 4;
      int gc = n0 + wc + n * 16 + (l & 15);
#pragma unroll
      for (int j = 0; j < 4; ++j)
        C[(size_t)(gr + j) * N + gc] = acc[m][n][j];
    }
}

// =================== fp32 GEMM fallback ===================
#define GBM 128
#define GBN 128
#define GBK 16
#define GPAD 4

__global__ __launch_bounds__(256)
void gemm_nt(const float* __restrict__ A, const float* __restrict__ Bm,
             float* __restrict__ C, int M, int N, int K) {
  __shared__ float Asf[GBK][GBM + GPAD];
  __shared__ float Bsf[GBK][GBN + GPAD];
  const int t  = threadIdx.x;
  const int m0 = blockIdx.y * GBM;
  const int n0 = blockIdx.x * GBN;
  const int tx = t & 15;
  const int ty = t >> 4;

  float acc[8][8];
#pragma unroll
  for (int i = 0; i < 8; ++i)
#pragma unroll
    for (int j = 0; j < 8; ++j) acc[i][j] = 0.f;

  for (int k0 = 0; k0 < K; k0 += GBK) {
#pragma unroll
    for (int i = 0; i < 2; ++i) {
      int f   = t + i * 256;
      int row = f >> 2;
      int kc  = (f & 3) << 2;
      float4 va = *(const float4*)(A + (size_t)(m0 + row) * K + k0 + kc);
      Asf[kc + 0][row] = va.x; Asf[kc + 1][row] = va.y;
      Asf[kc + 2][row] = va.z; Asf[kc + 3][row] = va.w;
      float4 vb = *(const float4*)(Bm + (size_t)(n0 + row) * K + k0 + kc);
      Bsf[kc + 0][row] = vb.x; Bsf[kc + 1][row] = vb.y;
      Bsf[kc + 2][row] = vb.z; Bsf[kc + 3][row] = vb.w;
    }
    __syncthreads();
#pragma unroll
    for (int kk = 0; kk < GBK; ++kk) {
      float a[8], b[8];
#pragma unroll
      for (int i = 0; i < 8; ++i) a[i] = Asf[kk][ty * 8 + i];
#pragma unroll
      for (int j = 0; j < 8; ++j) b[j] = Bsf[kk][tx * 8 + j];
#pragma unroll
      for (int i = 0; i < 8; ++i)
#pragma unroll
        for (int j = 0; j < 8; ++j) acc[i][j] += a[i] * b[j];
    }
    __syncthreads();
  }
#pragma unroll
  for (int i = 0; i < 8; ++i) {
    float* crow = C + (size_t)(m0 + ty * 8 + i) * N + n0 + tx * 8;
    *(float4*)(crow)     = make_float4(acc[i][0], acc[i][1], acc[i][2], acc[i][3]);
    *(float4*)(crow + 4) = make_float4(acc[i][4], acc[i][5], acc[i][6], acc[i][7]);
  }
}

// ---------------- RoPE cos/sin tables ----------------
__global__ void rope_tables(float* __restrict__ ctab, float* __restrict__ stab) {
  int idx = blockIdx.x * 256 + threadIdx.x;
  if (idx >= L_ * 32) return;
  int l = idx >> 5;
  int i = idx & 31;
  float freq = powf(10000.0f, -(float)(2 * i) / 64.0f);
  float ang  = (float)l * freq;
  ctab[idx] = cosf(ang);
  stab[idx] = sinf(ang);
}

// ---------------- RoPE in place on Q (scaled) and K ----------------
__global__ __launch_bounds__(256)
void rope_inplace(float* __restrict__ qkv, const float* __restrict__ ctab,
                  const float* __restrict__ stab) {
  const int row = blockIdx.x;
  const int l   = row & (L_ - 1);
  float* p = qkv + (size_t)row * OP;
  const int t = threadIdx.x;
#pragma unroll
  for (int k = 0; k < 5; ++k) {
    int item = t + k * 256;
    int hh = item >> 5;
    int d  = item & 31;
    int off = (hh < NH) ? hh * HD + d : KPOS + (hh - NH) * HD + d;
    float sc = (hh < NH) ? SCALE_ : 1.0f;
    float c = ctab[l * 32 + d];
    float s = stab[l * 32 + d];
    float a = p[off];
    float bq = p[off + 32];
    p[off]      = (a * c - bq * s) * sc;
    p[off + 32] = (bq * c + a * s) * sc;
  }
}

// =================== MFMA flash attention (split-bf16, causal, GQA) ========
// Block = (q-tile 64, head, batch), 4 waves. Wave w owns q rows w*16..w*16+15.
// S = Q K^T via mfma(Q-frag, K-frag); O^T = V^T P^T via mfma(VT-frag, S-frag).
// LDS fragment-major layout: chunk(row,kc) = ((row>>4)*8 + kc)*16 + (row&15),
// 8 bf16 elems per chunk -> every wave operand read = 64 consecutive 16B lines
// (conflict-free). Planes: [0]=hi, [1]=lo for 3-term split products.
#define CHUNK(row, kc) ((((row) >> 4) * 8 + (kc)) * 16 + ((row) & 15))

__global__ __launch_bounds__(256, 2)
void attn_fwd3(const float* __restrict__ qkv, float* __restrict__ out) {
  __shared__ __align__(16) unsigned short Kf[2][4096];   // K  [krow][d]
  __shared__ __align__(16) unsigned short Vf[2][4096];   // V^T[d][k]
  __shared__ __align__(16) unsigned short Sf[2][4096];   // P  [q][k]

  const int t   = threadIdx.x;
  const int qt  = blockIdx.x;
  const int h   = blockIdx.y;
  const int b   = blockIdx.z;
  const int kvh = h >> 2;
  const int w   = t >> 6;
  const int l   = t & 63;
  const int r15 = l & 15;
  const int g   = l >> 4;          // 0..3
  const float* base = qkv + (size_t)b * L_ * OP;

  // staging map: row/d = t&63, chunk pair pb, pb+1
  const int srow = t & 63;
  const int pb   = (t >> 6) * 2;

  // ---- Q fragments in registers (RoPE+scale already applied in global) ----
  s16x8 qhi[2], qlo[2];
  {
    const int qrow = qt * 64 + w * 16 + r15;
    const float* qsrc = base + (size_t)qrow * OP + h * HD + g * 8;
#pragma unroll
    for (int ks = 0; ks < 2; ++ks) {
      float4 a = *(const float4*)(qsrc + ks * 32);
      float4 c = *(const float4*)(qsrc + ks * 32 + 4);
      float v[8] = {a.x, a.y, a.z, a.w, c.x, c.y, c.z, c.w};
#pragma unroll
      for (int j = 0; j < 8; ++j) {
        unsigned short hh = f2bf(v[j]);
        qhi[ks][j] = (short)hh;
        qlo[ks][j] = (short)f2bf(v[j] - bf2f(hh));
      }
    }
  }

  f32x4 acco[4];                 // O^T: rows d = m*16+g*4+reg, col q = w*16+r15
  float m_run[4], l_run[4];
#pragma unroll
  for (int m = 0; m < 4; ++m)
#pragma unroll
    for (int q = 0; q < 4; ++q) acco[m][q] = 0.f;
#pragma unroll
  for (int q = 0; q < 4; ++q) { m_run[q] = NEG_BIG; l_run[q] = 0.f; }

  for (int kt = 0; kt <= qt; ++kt) {
    // ---- stage K rows (hi/lo) ----
    {
      const float* gk = base + (size_t)(kt * 64 + srow) * OP + KPOS + kvh * HD + pb * 8;
      float kv[16];
#pragma unroll
      for (int i = 0; i < 4; ++i) {
        float4 u = *(const float4*)(gk + 4 * i);
        kv[4 * i] = u.x; kv[4 * i + 1] = u.y; kv[4 * i + 2] = u.z; kv[4 * i + 3] = u.w;
      }
      s16x8 h0, h1, l0, l1;
#pragma unroll
      for (int j = 0; j < 8; ++j) {
        unsigned short hh = f2bf(kv[j]);
        h0[j] = (short)hh; l0[j] = (short)f2bf(kv[j] - bf2f(hh));
        unsigned short h2 = f2bf(kv[j + 8]);
        h1[j] = (short)h2; l1[j] = (short)f2bf(kv[j + 8] - bf2f(h2));
      }
      *(s16x8*)&Kf[0][CHUNK(srow, pb) * 8]     = h0;
      *(s16x8*)&Kf[0][CHUNK(srow, pb + 1) * 8] = h1;
      *(s16x8*)&Kf[1][CHUNK(srow, pb) * 8]     = l0;
      *(s16x8*)&Kf[1][CHUNK(srow, pb + 1) * 8] = l1;
    }
    // ---- stage V transposed (hi/lo): thread owns d=srow, k = pb*8..pb*8+15 ----
    {
      const float* gv = base + (size_t)(kt * 64 + pb * 8) * OP + VPOS + kvh * HD + srow;
      s16x8 h0, h1, l0, l1;
#pragma unroll
      for (int kk = 0; kk < 8; ++kk) {
        float v0 = gv[(size_t)kk * OP];
        float v1 = gv[(size_t)(kk + 8) * OP];
        unsigned short hh = f2bf(v0);
        h0[kk] = (short)hh; l0[kk] = (short)f2bf(v0 - bf2f(hh));
        unsigned short h2 = f2bf(v1);
        h1[kk] = (short)h2; l1[kk] = (short)f2bf(v1 - bf2f(h2));
      }
      *(s16x8*)&Vf[0][CHUNK(srow, pb) * 8]     = h0;
      *(s16x8*)&Vf[0][CHUNK(srow, pb + 1) * 8] = h1;
      *(s16x8*)&Vf[1][CHUNK(srow, pb) * 8]     = l0;
      *(s16x8*)&Vf[1][CHUNK(srow, pb + 1) * 8] = l1;
    }
    __syncthreads();

    // ---- S = Q K^T : 1x4 fragments, rows w*16..+15, cols 0..63 ----
    f32x4 accs[4];
#pragma unroll
    for (int n = 0; n < 4; ++n)
#pragma unroll
      for (int q = 0; q < 4; ++q) accs[n][q] = 0.f;

#pragma unroll
    for (int ks = 0; ks < 2; ++ks) {
      const int kc = ks * 4 + g;
#pragma unroll
      for (int n = 0; n < 4; ++n) {
        s16x8 bh = *(const s16x8*)&Kf[0][CHUNK(n * 16 + r15, kc) * 8];
        s16x8 bl = *(const s16x8*)&Kf[1][CHUNK(n * 16 + r15, kc) * 8];
        accs[n] = __builtin_amdgcn_mfma_f32_16x16x32_bf16(qhi[ks], bh, accs[n], 0, 0, 0);
        accs[n] = __builtin_amdgcn_mfma_f32_16x16x32_bf16(qlo[ks], bh, accs[n], 0, 0, 0);
        accs[n] = __builtin_amdgcn_mfma_f32_16x16x32_bf16(qhi[ks], bl, accs[n], 0, 0, 0);
      }
    }

    // ---- causal mask on diagonal tile ----
    if (kt == qt) {
#pragma unroll
      for (int n = 0; n < 4; ++n) {
        int col = n * 16 + r15;
#pragma unroll
        for (int q = 0; q < 4; ++q) {
          int row = w * 16 + g * 4 + q;
          if (col > row) accs[n][q] = NEG_BIG;
        }
      }
    }

    // ---- online softmax (S-layout: lane holds rows g*4+reg, cols n*16+r15) --
    float alpha[4];
#pragma unroll
    for (int q = 0; q < 4; ++q) {
      float mx = fmaxf(fmaxf(accs[0][q], accs[1][q]), fmaxf(accs[2][q], accs[3][q]));
      mx = fmaxf(mx, __shfl_xor(mx, 1));
      mx = fmaxf(mx, __shfl_xor(mx, 2));
      mx = fmaxf(mx, __shfl_xor(mx, 4));
      mx = fmaxf(mx, __shfl_xor(mx, 8));
      float mnew = fmaxf(m_run[q], mx);
      alpha[q] = __expf(m_run[q] - mnew);
      float ps = 0.f;
#pragma unroll
      for (int n = 0; n < 4; ++n) {
        float p = __expf(accs[n][q] - mnew);
        accs[n][q] = p;
        ps += p;
      }
      ps += __shfl_xor(ps, 1);
      ps += __shfl_xor(ps, 2);
      ps += __shfl_xor(ps, 4);
      ps += __shfl_xor(ps, 8);
      l_run[q] = l_run[q] * alpha[q] + ps;
      m_run[q] = mnew;
    }

    // ---- write P (hi/lo) to Sf in fragment-major layout ----
#pragma unroll
    for (int n = 0; n < 4; ++n) {
      const int kc = n * 2 + (r15 >> 3);
#pragma unroll
      for (int q = 0; q < 4; ++q) {
        int e = CHUNK(w * 16 + g * 4 + q, kc) * 8 + (l & 7);
        float p = accs[n][q];
        unsigned short hh = f2bf(p);
        Sf[0][e] = hh;
        Sf[1][e] = f2bf(p - bf2f(hh));
      }
    }

    // ---- rescale O^T by alpha[q] (q = r15 in O^T layout) via shuffles ----
    {
      int src = (r15 >> 2) << 4;
      float a0 = __shfl(alpha[0], src);
      float a1 = __shfl(alpha[1], src);
      float a2 = __shfl(alpha[2], src);
      float a3 = __shfl(alpha[3], src);
      int sel = r15 & 3;
      float aq = (sel == 0) ? a0 : (sel == 1) ? a1 : (sel == 2) ? a2 : a3;
#pragma unroll
      for (int m = 0; m < 4; ++m)
#pragma unroll
        for (int q = 0; q < 4; ++q) acco[m][q] *= aq;
    }

    // ---- O^T += V^T P^T : 4x1 fragments (d-rows x wave's 16 q-cols) ----
#pragma unroll
    for (int ks = 0; ks < 2; ++ks) {
      const int kc = ks * 4 + g;
      s16x8 bh = *(const s16x8*)&Sf[0][CHUNK(w * 16 + r15, kc) * 8];
      s16x8 bl = *(const s16x8*)&Sf[1][CHUNK(w * 16 + r15, kc) * 8];
#pragma unroll
      for (int m = 0; m < 4; ++m) {
        s16x8 ah = *(const s16x8*)&Vf[0][CHUNK(m * 16 + r15, kc) * 8];
        s16x8 al = *(const s16x8*)&Vf[1][CHUNK(m * 16 + r15, kc) * 8];
        acco[m] = __builtin_amdgcn_mfma_f32_16x16x32_bf16(ah, bh, acco[m], 0, 0, 0);
        acco[m] = __builtin_amdgcn_mfma_f32_16x16x32_bf16(al, bh, acco[m], 0, 0, 0);
        acco[m] = __builtin_amdgcn_mfma_f32_16x16x32_bf16(ah, bl, acco[m], 0, 0, 0);
      }
    }
    __syncthreads();   // protect Kf/Vf before next staging
  }

  // ---- normalize (1/l_run routed to O^T layout) + store ----
  {
    int src = (r15 >> 2) << 4;
    float i0 = __shfl(1.f / l_run[0], src);
    float i1 = __shfl(1.f / l_run[1], src);
    float i2 = __shfl(1.f / l_run[2], src);
    float i3 = __shfl(1.f / l_run[3], src);
    int sel = r15 & 3;
    float invq = (sel == 0) ? i0 : (sel == 1) ? i1 : (sel == 2) ? i2 : i3;
    const int qrow = qt * 64 + w * 16 + r15;
    float* dst = out + (size_t)(b * L_ + qrow) * QPOS + h * HD + g * 4;
#pragma unroll
    for (int m = 0; m < 4; ++m) {
      *(float4*)(dst + m * 16) = make_float4(acco[m][0] * invq, acco[m][1] * invq,
                                             acco[m][2] * invq, acco[m][3] * invq);
    }
  }
}

// ---------------- launch ----------------
extern "C" void kernel_launch(void* const* d_in, const int* in_sizes, int n_in,
                              void* d_out, int out_size, void* d_ws, size_t ws_size,
                              hipStream_t stream) {
  const float* x    = (const float*)d_in[0];   // [B,L,D]
  const float* Wqkv = (const float*)d_in[1];   // [OP,D]
  const float* Wo   = (const float*)d_in[2];   // [D, NH*HD]
  float* outp = (float*)d_out;
  float* ws   = (float*)d_ws;

  float* qkv_ws  = ws;
  float* attn_ws = qkv_ws + (size_t)(B_ * L_) * OP;
  float* ctab    = attn_ws + (size_t)(B_ * L_) * QPOS;
  float* stab    = ctab + (size_t)L_ * 32;
  unsigned short* A2 = (unsigned short*)(stab + (size_t)L_ * 32);
  unsigned short* B2 = A2 + (size_t)4096 * 6144;

  const size_t NEED = ((size_t)21102592) * 4 + ((size_t)44040192) * 2;
  const bool mfma_ok = ws_size >= NEED;

  if (mfma_ok) {
    split3<<<dim3(B_ * L_), 256, 0, stream>>>(x, A2, D_, 0);
    split3<<<dim3(OP), 256, 0, stream>>>(Wqkv, B2, D_, 1);
    gemm_bt_bf16<<<dim3(OP / TBN, (B_ * L_) / TBM), 256, 0, stream>>>(
        A2, B2, qkv_ws, B_ * L_, OP, 3 * D_);
  } else {
    gemm_nt<<<dim3(OP / GBN, (B_ * L_) / GBM), 256, 0, stream>>>(
        x, Wqkv, qkv_ws, B_ * L_, OP, D_);
  }

  rope_tables<<<dim3((L_ * 32 + 255) / 256), 256, 0, stream>>>(ctab, stab);
  rope_inplace<<<dim3(B_ * L_), 256, 0, stream>>>(qkv_ws, ctab, stab);

  dim3 ga(L_ / 64, NH, B_);
  attn_fwd3<<<ga, 256, 0, stream>>>(qkv_ws, attn_ws);

  if (mfma_ok) {
    split3<<<dim3(B_ * L_), 256, 0, stream>>>(attn_ws, A2, QPOS, 0);
    split3<<<dim3(D_), 256, 0, stream>>>(Wo, B2, QPOS, 1);
    gemm_bt_bf16<<<dim3(D_ / TBN, (B_ * L_) / TBM), 256, 0, stream>>>(
        A2, B2, outp, B_ * L_, D_, 3 * QPOS);
  } else {
    gemm_nt<<<dim3(D_ / GBN, (B_ * L_) / GBM), 256, 0, stream>>>(
        attn_ws, Wo, outp, B_ * L_, D_, QPOS);
  }
}

// Round 5
// 826.659 us; speedup vs baseline: 8.2506x; 1.1512x over previous
//
#include <hip/hip_runtime.h>
#include <math.h>

// Problem constants
#define B_   2
#define L_   2048
#define D_   2048
#define NH   32
#define NKV  8
#define HD   64
#define OP   3072          // NH*HD + 2*NKV*HD
#define QPOS 2048
#define KPOS 2048
#define VPOS 2560
#define SCALE_ 0.125f
#define NEG_BIG -1.0e30f

typedef __attribute__((ext_vector_type(8))) short s16x8;   // 8 bf16 in 4 VGPRs
typedef __attribute__((ext_vector_type(4))) short s16x4;
typedef __attribute__((ext_vector_type(4))) float f32x4;

// ---- bf16 helpers ----
__device__ __forceinline__ unsigned short f2bf(float f) {
  unsigned int u = __float_as_uint(f);
  u += 0x7fffu + ((u >> 16) & 1u);         // RNE
  return (unsigned short)(u >> 16);
}
__device__ __forceinline__ float bf2f(unsigned short h) {
  return __uint_as_float((unsigned int)h << 16);
}

// ---- async global->LDS, 16B per lane ----
__device__ __forceinline__ void gload16(const unsigned short* g, unsigned short* l) {
  __builtin_amdgcn_global_load_lds(
      (const __attribute__((address_space(1))) unsigned int*)g,
      (__attribute__((address_space(3))) unsigned int*)l, 16, 0, 0);
}

// Fragment-major chunk layout (8 bf16 elems per chunk, 16B):
#define CHUNK(row, kc) ((((row) >> 4) * 8 + (kc)) * 16 + ((row) & 15))

// =================== split: fp32 [R][K] -> bf16 [R][3K] ===================
// mode 0 (A-side): [hi | lo | hi]    mode 1 (B-side): [hi | hi | lo]
__global__ __launch_bounds__(256)
void split3(const float* __restrict__ src, unsigned short* __restrict__ dst,
            int K, int mode) {
  const int r = blockIdx.x;
  const int c = threadIdx.x * 8;
  const float* s = src + (size_t)r * K + c;
  float4 v0 = *(const float4*)s;
  float4 v1 = *(const float4*)(s + 4);
  float v[8] = {v0.x, v0.y, v0.z, v0.w, v1.x, v1.y, v1.z, v1.w};
  unsigned short hi[8], lo[8];
#pragma unroll
  for (int j = 0; j < 8; ++j) {
    hi[j] = f2bf(v[j]);
    lo[j] = f2bf(v[j] - bf2f(hi[j]));
  }
  unsigned short* d = dst + (size_t)r * 3 * K;
  s16x8 hv, lv;
#pragma unroll
  for (int j = 0; j < 8; ++j) { hv[j] = (short)hi[j]; lv[j] = (short)lo[j]; }
  *(s16x8*)(d + c)         = hv;
  *(s16x8*)(d + K + c)     = (mode == 0) ? lv : hv;
  *(s16x8*)(d + 2 * K + c) = (mode == 0) ? hv : lv;
}

// =================== bf16 NT GEMM (m97 structure, unchanged) ===============
#define TBM 128
#define TBN 128
#define TBK 64

__global__ __launch_bounds__(256)
void gemm_bt_bf16(const unsigned short* __restrict__ A2,
                  const unsigned short* __restrict__ B2,
                  float* __restrict__ C, int M, int N, int K2) {
  __shared__ unsigned short As[TBM * TBK];
  __shared__ unsigned short Bs[TBN * TBK];

  const int t  = threadIdx.x;
  const int m0 = blockIdx.y * TBM;
  const int n0 = blockIdx.x * TBN;
  const int w  = t >> 6;
  const int l  = t & 63;
  const int wr = (w >> 1) * 64;
  const int wc = (w & 1) * 64;
  const int srow = t >> 3;
  const int scol = (t & 7) * 8;

  f32x4 acc[4][4];
#pragma unroll
  for (int m = 0; m < 4; ++m)
#pragma unroll
    for (int n = 0; n < 4; ++n)
#pragma unroll
      for (int q = 0; q < 4; ++q) acc[m][n][q] = 0.f;

  const int nsteps = K2 / TBK;
  for (int ks = 0; ks < nsteps; ++ks) {
    const size_t kb = (size_t)ks * TBK;
#pragma unroll
    for (int i = 0; i < 4; ++i) {
      int row = i * 32 + srow;
      gload16(A2 + (size_t)(m0 + row) * K2 + kb + scol, &As[row * TBK + scol]);
      gload16(B2 + (size_t)(n0 + row) * K2 + kb + scol, &Bs[row * TBK + scol]);
    }
    __syncthreads();

#pragma unroll
    for (int kk = 0; kk < 2; ++kk) {
      s16x8 af[4], bf[4];
      const int ko = kk * 32 + (l >> 4) * 8;
#pragma unroll
      for (int m = 0; m < 4; ++m)
        af[m] = *(const s16x8*)&As[(wr + m * 16 + (l & 15)) * TBK + ko];
#pragma unroll
      for (int n = 0; n < 4; ++n)
        bf[n] = *(const s16x8*)&Bs[(wc + n * 16 + (l & 15)) * TBK + ko];
#pragma unroll
      for (int m = 0; m < 4; ++m)
#pragma unroll
        for (int n = 0; n < 4; ++n)
          acc[m][n] = __builtin_amdgcn_mfma_f32_16x16x32_bf16(af[m], bf[n], acc[m][n], 0, 0, 0);
    }
    __syncthreads();
  }

#pragma unroll
  for (int m = 0; m < 4; ++m)
#pragma unroll
    for (int n = 0; n < 4; ++n) {
      int gr = m0 + wr + m * 16 + (l >> 4) * 4;
      int gc = n0 + wc + n * 16 + (l & 15);
#pragma unroll
      for (int j = 0; j < 4; ++j)
        C[(size_t)(gr + j) * N + gc] = acc[m][n][j];
    }
}

// =================== fp32 GEMM fallback ===================
#define GBM 128
#define GBN 128
#define GBK 16
#define GPAD 4

__global__ __launch_bounds__(256)
void gemm_nt(const float* __restrict__ A, const float* __restrict__ Bm,
             float* __restrict__ C, int M, int N, int K) {
  __shared__ float Asf[GBK][GBM + GPAD];
  __shared__ float Bsf[GBK][GBN + GPAD];
  const int t  = threadIdx.x;
  const int m0 = blockIdx.y * GBM;
  const int n0 = blockIdx.x * GBN;
  const int tx = t & 15;
  const int ty = t >> 4;

  float acc[8][8];
#pragma unroll
  for (int i = 0; i < 8; ++i)
#pragma unroll
    for (int j = 0; j < 8; ++j) acc[i][j] = 0.f;

  for (int k0 = 0; k0 < K; k0 += GBK) {
#pragma unroll
    for (int i = 0; i < 2; ++i) {
      int f   = t + i * 256;
      int row = f >> 2;
      int kc  = (f & 3) << 2;
      float4 va = *(const float4*)(A + (size_t)(m0 + row) * K + k0 + kc);
      Asf[kc + 0][row] = va.x; Asf[kc + 1][row] = va.y;
      Asf[kc + 2][row] = va.z; Asf[kc + 3][row] = va.w;
      float4 vb = *(const float4*)(Bm + (size_t)(n0 + row) * K + k0 + kc);
      Bsf[kc + 0][row] = vb.x; Bsf[kc + 1][row] = vb.y;
      Bsf[kc + 2][row] = vb.z; Bsf[kc + 3][row] = vb.w;
    }
    __syncthreads();
#pragma unroll
    for (int kk = 0; kk < GBK; ++kk) {
      float a[8], b[8];
#pragma unroll
      for (int i = 0; i < 8; ++i) a[i] = Asf[kk][ty * 8 + i];
#pragma unroll
      for (int j = 0; j < 8; ++j) b[j] = Bsf[kk][tx * 8 + j];
#pragma unroll
      for (int i = 0; i < 8; ++i)
#pragma unroll
        for (int j = 0; j < 8; ++j) acc[i][j] += a[i] * b[j];
    }
    __syncthreads();
  }
#pragma unroll
  for (int i = 0; i < 8; ++i) {
    float* crow = C + (size_t)(m0 + ty * 8 + i) * N + n0 + tx * 8;
    *(float4*)(crow)     = make_float4(acc[i][0], acc[i][1], acc[i][2], acc[i][3]);
    *(float4*)(crow + 4) = make_float4(acc[i][4], acc[i][5], acc[i][6], acc[i][7]);
  }
}

// ---------------- RoPE cos/sin tables ----------------
__global__ void rope_tables(float* __restrict__ ctab, float* __restrict__ stab) {
  int idx = blockIdx.x * 256 + threadIdx.x;
  if (idx >= L_ * 32) return;
  int l = idx >> 5;
  int i = idx & 31;
  float freq = powf(10000.0f, -(float)(2 * i) / 64.0f);
  float ang  = (float)l * freq;
  ctab[idx] = cosf(ang);
  stab[idx] = sinf(ang);
}

// ---------------- RoPE in place on Q (scaled) and K ----------------
__global__ __launch_bounds__(256)
void rope_inplace(float* __restrict__ qkv, const float* __restrict__ ctab,
                  const float* __restrict__ stab) {
  const int row = blockIdx.x;
  const int l   = row & (L_ - 1);
  float* p = qkv + (size_t)row * OP;
  const int t = threadIdx.x;
#pragma unroll
  for (int k = 0; k < 5; ++k) {
    int item = t + k * 256;
    int hh = item >> 5;
    int d  = item & 31;
    int off = (hh < NH) ? hh * HD + d : KPOS + (hh - NH) * HD + d;
    float sc = (hh < NH) ? SCALE_ : 1.0f;
    float c = ctab[l * 32 + d];
    float s = stab[l * 32 + d];
    float a = p[off];
    float bq = p[off + 32];
    p[off]      = (a * c - bq * s) * sc;
    p[off + 32] = (bq * c + a * s) * sc;
  }
}

// =================== pre-split K and V^T into tiled bf16 hi/lo =============
// Per (b,kvh,kt) tile: 8192 u16 = [plane hi 4096 | plane lo 4096], each plane
// the exact LDS image in CHUNK layout. K: row=krow, elems along d.
// V: row=d (transposed), elems along k.
__global__ __launch_bounds__(256)
void split_kv(const float* __restrict__ qkv, unsigned short* __restrict__ Ksp,
              unsigned short* __restrict__ Vsp) {
  const int kt = blockIdx.x, kvh = blockIdx.y, b = blockIdx.z;
  const int t = threadIdx.x;
  const int srow = t & 63;
  const int pb   = (t >> 6) * 2;
  const size_t tb = (((size_t)(b * NKV + kvh) * 32) + kt) * 8192;
  const float* base = qkv + (size_t)b * L_ * OP;

  // ---- K rows ----
  {
    const float* gk = base + (size_t)(kt * 64 + srow) * OP + KPOS + kvh * HD + pb * 8;
    float kv[16];
#pragma unroll
    for (int i = 0; i < 4; ++i) {
      float4 u = *(const float4*)(gk + 4 * i);
      kv[4 * i] = u.x; kv[4 * i + 1] = u.y; kv[4 * i + 2] = u.z; kv[4 * i + 3] = u.w;
    }
    s16x8 h0, h1, l0, l1;
#pragma unroll
    for (int j = 0; j < 8; ++j) {
      unsigned short hh = f2bf(kv[j]);
      h0[j] = (short)hh; l0[j] = (short)f2bf(kv[j] - bf2f(hh));
      unsigned short h2 = f2bf(kv[j + 8]);
      h1[j] = (short)h2; l1[j] = (short)f2bf(kv[j + 8] - bf2f(h2));
    }
    unsigned short* kd = Ksp + tb;
    *(s16x8*)&kd[CHUNK(srow, pb) * 8]            = h0;
    *(s16x8*)&kd[CHUNK(srow, pb + 1) * 8]        = h1;
    *(s16x8*)&kd[4096 + CHUNK(srow, pb) * 8]     = l0;
    *(s16x8*)&kd[4096 + CHUNK(srow, pb + 1) * 8] = l1;
  }
  // ---- V transposed: thread owns d=srow, k = pb*8 .. pb*8+15 ----
  {
    const float* gv = base + (size_t)(kt * 64 + pb * 8) * OP + VPOS + kvh * HD + srow;
    s16x8 h0, h1, l0, l1;
#pragma unroll
    for (int kk = 0; kk < 8; ++kk) {
      float v0 = gv[(size_t)kk * OP];
      float v1 = gv[(size_t)(kk + 8) * OP];
      unsigned short hh = f2bf(v0);
      h0[kk] = (short)hh; l0[kk] = (short)f2bf(v0 - bf2f(hh));
      unsigned short h2 = f2bf(v1);
      h1[kk] = (short)h2; l1[kk] = (short)f2bf(v1 - bf2f(h2));
    }
    unsigned short* vd = Vsp + tb;
    *(s16x8*)&vd[CHUNK(srow, pb) * 8]            = h0;
    *(s16x8*)&vd[CHUNK(srow, pb + 1) * 8]        = h1;
    *(s16x8*)&vd[4096 + CHUNK(srow, pb) * 8]     = l0;
    *(s16x8*)&vd[4096 + CHUNK(srow, pb + 1) * 8] = l1;
  }
}

// =================== MFMA flash attention v4 ===============================
// Staging = 8 async global_load_lds (zero VALU). Softmax denominator via
// ones-column MFMA (lands in O^T layout; no l_run bookkeeping). Output
// written directly as split-bf16 [hi|lo|hi] rows of A2 for the second GEMM.
__global__ __launch_bounds__(256, 2)
void attn_fwd4(const float* __restrict__ qkv,
               const unsigned short* __restrict__ Ksp,
               const unsigned short* __restrict__ Vsp,
               unsigned short* __restrict__ A2out) {
  __shared__ __align__(16) unsigned short Kf[2][4096];
  __shared__ __align__(16) unsigned short Vf[2][4096];
  __shared__ __align__(16) unsigned short Sf[2][4096];

  const int t   = threadIdx.x;
  const int qt  = blockIdx.x;
  const int h   = blockIdx.y;
  const int b   = blockIdx.z;
  const int kvh = h >> 2;
  const int w   = t >> 6;
  const int l   = t & 63;
  const int r15 = l & 15;
  const int g   = l >> 4;
  const float* base = qkv + (size_t)b * L_ * OP;

  // ---- Q fragments in registers (RoPE+scale already applied) ----
  s16x8 qhi[2], qlo[2];
  {
    const int qrow = qt * 64 + w * 16 + r15;
    const float* qsrc = base + (size_t)qrow * OP + h * HD + g * 8;
#pragma unroll
    for (int ks = 0; ks < 2; ++ks) {
      float4 a = *(const float4*)(qsrc + ks * 32);
      float4 c = *(const float4*)(qsrc + ks * 32 + 4);
      float v[8] = {a.x, a.y, a.z, a.w, c.x, c.y, c.z, c.w};
#pragma unroll
      for (int j = 0; j < 8; ++j) {
        unsigned short hh = f2bf(v[j]);
        qhi[ks][j] = (short)hh;
        qlo[ks][j] = (short)f2bf(v[j] - bf2f(hh));
      }
    }
  }

  s16x8 onesf;
#pragma unroll
  for (int j = 0; j < 8; ++j) onesf[j] = (short)0x3F80;   // bf16 1.0

  f32x4 acco[4];          // O^T: rows d = m*16+g*4+reg, col q = w*16+r15
  f32x4 acc1;             // ones-row: all regs = sum_k P[q][:]
  float m_run[4];
#pragma unroll
  for (int m = 0; m < 4; ++m)
#pragma unroll
    for (int q = 0; q < 4; ++q) acco[m][q] = 0.f;
#pragma unroll
  for (int q = 0; q < 4; ++q) acc1[q] = 0.f;
#pragma unroll
  for (int q = 0; q < 4; ++q) m_run[q] = NEG_BIG;

  for (int kt = 0; kt <= qt; ++kt) {
    // ---- async staging: global (pre-split tile image) -> LDS ----
    const size_t tb = (((size_t)(b * NKV + kvh) * 32) + kt) * 8192;
    const unsigned short* kt_k = Ksp + tb;
    const unsigned short* kt_v = Vsp + tb;
#pragma unroll
    for (int p = 0; p < 2; ++p)
#pragma unroll
      for (int i = 0; i < 2; ++i) {
        const int e = (i * 256 + t) * 8;
        gload16(kt_k + p * 4096 + e, &Kf[p][e]);
        gload16(kt_v + p * 4096 + e, &Vf[p][e]);
      }
    __syncthreads();   // drains vmcnt

    // ---- S = Q K^T ----
    f32x4 accs[4];
#pragma unroll
    for (int n = 0; n < 4; ++n)
#pragma unroll
      for (int q = 0; q < 4; ++q) accs[n][q] = 0.f;

#pragma unroll
    for (int ks = 0; ks < 2; ++ks) {
      const int kc = ks * 4 + g;
#pragma unroll
      for (int n = 0; n < 4; ++n) {
        s16x8 bh = *(const s16x8*)&Kf[0][CHUNK(n * 16 + r15, kc) * 8];
        s16x8 bl = *(const s16x8*)&Kf[1][CHUNK(n * 16 + r15, kc) * 8];
        accs[n] = __builtin_amdgcn_mfma_f32_16x16x32_bf16(qhi[ks], bh, accs[n], 0, 0, 0);
        accs[n] = __builtin_amdgcn_mfma_f32_16x16x32_bf16(qlo[ks], bh, accs[n], 0, 0, 0);
        accs[n] = __builtin_amdgcn_mfma_f32_16x16x32_bf16(qhi[ks], bl, accs[n], 0, 0, 0);
      }
    }

    // ---- causal mask on diagonal tile ----
    if (kt == qt) {
#pragma unroll
      for (int n = 0; n < 4; ++n) {
        int col = n * 16 + r15;
#pragma unroll
        for (int q = 0; q < 4; ++q) {
          int row = w * 16 + g * 4 + q;
          if (col > row) accs[n][q] = NEG_BIG;
        }
      }
    }

    // ---- online max + exp (S-layout); sums come via ones-MFMA ----
    float alpha[4];
#pragma unroll
    for (int q = 0; q < 4; ++q) {
      float mx = fmaxf(fmaxf(accs[0][q], accs[1][q]), fmaxf(accs[2][q], accs[3][q]));
      mx = fmaxf(mx, __shfl_xor(mx, 1));
      mx = fmaxf(mx, __shfl_xor(mx, 2));
      mx = fmaxf(mx, __shfl_xor(mx, 4));
      mx = fmaxf(mx, __shfl_xor(mx, 8));
      float mnew = fmaxf(m_run[q], mx);
      alpha[q] = __expf(m_run[q] - mnew);
      m_run[q] = mnew;
#pragma unroll
      for (int n = 0; n < 4; ++n) accs[n][q] = __expf(accs[n][q] - mnew);
    }

    // ---- write P (hi/lo) to Sf (wave-local rows; no barrier needed) ----
#pragma unroll
    for (int n = 0; n < 4; ++n) {
      const int kc = n * 2 + (r15 >> 3);
#pragma unroll
      for (int q = 0; q < 4; ++q) {
        int e = CHUNK(w * 16 + g * 4 + q, kc) * 8 + (l & 7);
        float p = accs[n][q];
        unsigned short hh = f2bf(p);
        Sf[0][e] = hh;
        Sf[1][e] = f2bf(p - bf2f(hh));
      }
    }

    // ---- rescale O^T (and ones-acc) by alpha routed to O-layout ----
    {
      int src = (r15 >> 2) << 4;
      float a0 = __shfl(alpha[0], src);
      float a1 = __shfl(alpha[1], src);
      float a2 = __shfl(alpha[2], src);
      float a3 = __shfl(alpha[3], src);
      int sel = r15 & 3;
      float aq = (sel == 0) ? a0 : (sel == 1) ? a1 : (sel == 2) ? a2 : a3;
#pragma unroll
      for (int m = 0; m < 4; ++m)
#pragma unroll
        for (int q = 0; q < 4; ++q) acco[m][q] *= aq;
#pragma unroll
      for (int q = 0; q < 4; ++q) acc1[q] *= aq;
    }

    // ---- O^T += V^T P^T ; ones-row accumulates sum(P) ----
#pragma unroll
    for (int ks = 0; ks < 2; ++ks) {
      const int kc = ks * 4 + g;
      s16x8 bh = *(const s16x8*)&Sf[0][CHUNK(w * 16 + r15, kc) * 8];
      s16x8 bl = *(const s16x8*)&Sf[1][CHUNK(w * 16 + r15, kc) * 8];
      acc1 = __builtin_amdgcn_mfma_f32_16x16x32_bf16(onesf, bh, acc1, 0, 0, 0);
      acc1 = __builtin_amdgcn_mfma_f32_16x16x32_bf16(onesf, bl, acc1, 0, 0, 0);
#pragma unroll
      for (int m = 0; m < 4; ++m) {
        s16x8 ah = *(const s16x8*)&Vf[0][CHUNK(m * 16 + r15, kc) * 8];
        s16x8 al = *(const s16x8*)&Vf[1][CHUNK(m * 16 + r15, kc) * 8];
        acco[m] = __builtin_amdgcn_mfma_f32_16x16x32_bf16(ah, bh, acco[m], 0, 0, 0);
        acco[m] = __builtin_amdgcn_mfma_f32_16x16x32_bf16(al, bh, acco[m], 0, 0, 0);
        acco[m] = __builtin_amdgcn_mfma_f32_16x16x32_bf16(ah, bl, acco[m], 0, 0, 0);
      }
    }
    __syncthreads();   // protect Kf/Vf before next staging
  }

  // ---- normalize + store split-bf16 directly into A2 [hi|lo|hi] ----
  {
    float invq = 1.f / acc1[0];
    const int qrow = qt * 64 + w * 16 + r15;
    unsigned short* arow = A2out + (size_t)(b * L_ + qrow) * (3 * QPOS) + h * HD + g * 4;
#pragma unroll
    for (int m = 0; m < 4; ++m) {
      s16x4 hv, lv;
#pragma unroll
      for (int j = 0; j < 4; ++j) {
        float v = acco[m][j] * invq;
        unsigned short hh = f2bf(v);
        hv[j] = (short)hh;
        lv[j] = (short)f2bf(v - bf2f(hh));
      }
      *(s16x4*)(arow + m * 16)            = hv;
      *(s16x4*)(arow + QPOS + m * 16)     = lv;
      *(s16x4*)(arow + 2 * QPOS + m * 16) = hv;
    }
  }
}

// ---------------- fp32 flash attention fallback (round-2 version) ----------
#define LDA 68

__global__ __launch_bounds__(256)
void attn_fwd2(const float* __restrict__ qkv, float* __restrict__ out) {
  __shared__ float QsT[HD][LDA];
  __shared__ float KsT[HD][LDA];
  __shared__ float Vs[64][LDA];
  __shared__ float SsT[64][LDA];

  const int t   = threadIdx.x;
  const int qt  = blockIdx.x;
  const int h   = blockIdx.y;
  const int b   = blockIdx.z;
  const int kvh = h >> 2;
  const int tx  = t & 15;
  const int ty  = t >> 4;
  const int r   = t >> 2;
  const int seg = t & 3;
  const float* base = qkv + (size_t)b * L_ * OP;

  {
    const float* src = base + (size_t)(qt * 64 + r) * OP + h * HD + seg * 16;
#pragma unroll
    for (int u = 0; u < 4; ++u) {
      float4 v = *(const float4*)(src + 4 * u);
      int d = seg * 16 + 4 * u;
      QsT[d + 0][r] = v.x; QsT[d + 1][r] = v.y;
      QsT[d + 2][r] = v.z; QsT[d + 3][r] = v.w;
    }
  }

  float m_run[4], l_run[4], o[4][4];
#pragma unroll
  for (int i = 0; i < 4; ++i) {
    m_run[i] = NEG_BIG; l_run[i] = 0.f;
#pragma unroll
    for (int j = 0; j < 4; ++j) o[i][j] = 0.f;
  }

  for (int kt = 0; kt <= qt; ++kt) {
    {
      const float* ksrc = base + (size_t)(kt * 64 + r) * OP + KPOS + kvh * HD + seg * 16;
      const float* vsrc = base + (size_t)(kt * 64 + r) * OP + VPOS + kvh * HD + seg * 16;
#pragma unroll
      for (int u = 0; u < 4; ++u) {
        float4 kv = *(const float4*)(ksrc + 4 * u);
        int d = seg * 16 + 4 * u;
        KsT[d + 0][r] = kv.x; KsT[d + 1][r] = kv.y;
        KsT[d + 2][r] = kv.z; KsT[d + 3][r] = kv.w;
        *(float4*)&Vs[r][seg * 16 + 4 * u] = *(const float4*)(vsrc + 4 * u);
      }
    }
    __syncthreads();

    float s4[4][4];
#pragma unroll
    for (int i = 0; i < 4; ++i)
#pragma unroll
      for (int j = 0; j < 4; ++j) s4[i][j] = 0.f;

#pragma unroll 4
    for (int d = 0; d < 64; ++d) {
      float4 qa = *(const float4*)&QsT[d][ty * 4];
      float4 kb = *(const float4*)&KsT[d][tx * 4];
      float a[4] = {qa.x, qa.y, qa.z, qa.w};
      float bb[4] = {kb.x, kb.y, kb.z, kb.w};
#pragma unroll
      for (int i = 0; i < 4; ++i)
#pragma unroll
        for (int j = 0; j < 4; ++j) s4[i][j] += a[i] * bb[j];
    }

    if (kt == qt) {
#pragma unroll
      for (int i = 0; i < 4; ++i)
#pragma unroll
        for (int j = 0; j < 4; ++j)
          if (tx * 4 + j > ty * 4 + i) s4[i][j] = NEG_BIG;
    }

#pragma unroll
    for (int i = 0; i < 4; ++i) {
      float mloc = fmaxf(fmaxf(s4[i][0], s4[i][1]), fmaxf(s4[i][2], s4[i][3]));
      mloc = fmaxf(mloc, __shfl_xor(mloc, 1));
      mloc = fmaxf(mloc, __shfl_xor(mloc, 2));
      mloc = fmaxf(mloc, __shfl_xor(mloc, 4));
      mloc = fmaxf(mloc, __shfl_xor(mloc, 8));
      float mnew  = fmaxf(m_run[i], mloc);
      float alpha = __expf(m_run[i] - mnew);
      float psum  = 0.f;
#pragma unroll
      for (int j = 0; j < 4; ++j) {
        float pv = __expf(s4[i][j] - mnew);
        s4[i][j] = pv;
        psum += pv;
      }
      psum += __shfl_xor(psum, 1);
      psum += __shfl_xor(psum, 2);
      psum += __shfl_xor(psum, 4);
      psum += __shfl_xor(psum, 8);
      l_run[i] = l_run[i] * alpha + psum;
      m_run[i] = mnew;
#pragma unroll
      for (int j = 0; j < 4; ++j) o[i][j] *= alpha;
    }

#pragma unroll
    for (int j = 0; j < 4; ++j)
#pragma unroll
      for (int i = 0; i < 4; ++i)
        SsT[tx * 4 + j][ty * 4 + i] = s4[i][j];
    __syncthreads();

#pragma unroll 4
    for (int k = 0; k < 64; ++k) {
      float4 pa = *(const float4*)&SsT[k][ty * 4];
      float4 vb = *(const float4*)&Vs[k][tx * 4];
      float a[4] = {pa.x, pa.y, pa.z, pa.w};
      float bb[4] = {vb.x, vb.y, vb.z, vb.w};
#pragma unroll
      for (int i = 0; i < 4; ++i)
#pragma unroll
        for (int j = 0; j < 4; ++j) o[i][j] += a[i] * bb[j];
    }
    __syncthreads();
  }

#pragma unroll
  for (int i = 0; i < 4; ++i) {
    float inv = 1.f / l_run[i];
    float* dst = out + ((size_t)(b * L_ + qt * 64 + ty * 4 + i)) * QPOS + h * HD + tx * 4;
    *(float4*)dst = make_float4(o[i][0] * inv, o[i][1] * inv,
                                o[i][2] * inv, o[i][3] * inv);
  }
}

// ---------------- launch ----------------
extern "C" void kernel_launch(void* const* d_in, const int* in_sizes, int n_in,
                              void* d_out, int out_size, void* d_ws, size_t ws_size,
                              hipStream_t stream) {
  const float* x    = (const float*)d_in[0];   // [B,L,D]
  const float* Wqkv = (const float*)d_in[1];   // [OP,D]
  const float* Wo   = (const float*)d_in[2];   // [D, NH*HD]
  float* outp = (float*)d_out;
  float* ws   = (float*)d_ws;

  float* qkv_ws  = ws;                                   // 12.58M f32
  float* attn_ws = qkv_ws + (size_t)(B_ * L_) * OP;      //  8.39M f32 (fallback only)
  float* ctab    = attn_ws + (size_t)(B_ * L_) * QPOS;
  float* stab    = ctab + (size_t)L_ * 32;
  unsigned short* A2 = (unsigned short*)(stab + (size_t)L_ * 32);
  unsigned short* B2 = A2 + (size_t)4096 * 6144;

  // In the MFMA path attn_ws is unused -> alias the pre-split K/V tiles there.
  unsigned short* Ksp = (unsigned short*)attn_ws;        // 4M u16 = 8MB
  unsigned short* Vsp = Ksp + (size_t)B_ * NKV * 32 * 8192;

  const size_t NEED = ((size_t)21102592) * 4 + ((size_t)44040192) * 2;  // 172.5MB
  const bool mfma_ok = ws_size >= NEED;

  if (mfma_ok) {
    // 1) QKV projection via split-bf16 MFMA
    split3<<<dim3(B_ * L_), 256, 0, stream>>>(x, A2, D_, 0);
    split3<<<dim3(OP), 256, 0, stream>>>(Wqkv, B2, D_, 1);
    gemm_bt_bf16<<<dim3(OP / TBN, (B_ * L_) / TBM), 256, 0, stream>>>(
        A2, B2, qkv_ws, B_ * L_, OP, 3 * D_);

    // 2) RoPE
    rope_tables<<<dim3((L_ * 32 + 255) / 256), 256, 0, stream>>>(ctab, stab);
    rope_inplace<<<dim3(B_ * L_), 256, 0, stream>>>(qkv_ws, ctab, stab);

    // 3) pre-split K/V tiles, then MFMA attention -> writes A2 directly
    split_kv<<<dim3(32, NKV, B_), 256, 0, stream>>>(qkv_ws, Ksp, Vsp);
    attn_fwd4<<<dim3(L_ / 64, NH, B_), 256, 0, stream>>>(qkv_ws, Ksp, Vsp, A2);

    // 4) output projection
    split3<<<dim3(D_), 256, 0, stream>>>(Wo, B2, QPOS, 1);
    gemm_bt_bf16<<<dim3(D_ / TBN, (B_ * L_) / TBM), 256, 0, stream>>>(
        A2, B2, outp, B_ * L_, D_, 3 * QPOS);
  } else {
    gemm_nt<<<dim3(OP / GBN, (B_ * L_) / GBM), 256, 0, stream>>>(
        x, Wqkv, qkv_ws, B_ * L_, OP, D_);
    rope_tables<<<dim3((L_ * 32 + 255) / 256), 256, 0, stream>>>(ctab, stab);
    rope_inplace<<<dim3(B_ * L_), 256, 0, stream>>>(qkv_ws, ctab, stab);
    attn_fwd2<<<dim3(L_ / 64, NH, B_), 256, 0, stream>>>(qkv_ws, attn_ws);
    gemm_nt<<<dim3(D_ / GBN, (B_ * L_) / GBM), 256, 0, stream>>>(
        attn_ws, Wo, outp, B_ * L_, D_, QPOS);
  }
}

// Round 6
// 796.074 us; speedup vs baseline: 8.5676x; 1.0384x over previous
//
#include <hip/hip_runtime.h>
#include <math.h>

// Problem constants
#define B_   2
#define L_   2048
#define D_   2048
#define NH   32
#define NKV  8
#define HD   64
#define OP   3072          // NH*HD + 2*NKV*HD
#define QPOS 2048
#define KPOS 2048
#define VPOS 2560
#define SCALE_ 0.125f
#define NEG_BIG -1.0e30f

typedef __attribute__((ext_vector_type(8))) short s16x8;   // 8 bf16 in 4 VGPRs
typedef __attribute__((ext_vector_type(4))) short s16x4;
typedef __attribute__((ext_vector_type(4))) float f32x4;

// ---- bf16 helpers ----
__device__ __forceinline__ unsigned short f2bf(float f) {
  unsigned int u = __float_as_uint(f);
  u += 0x7fffu + ((u >> 16) & 1u);         // RNE
  return (unsigned short)(u >> 16);
}
__device__ __forceinline__ float bf2f(unsigned short h) {
  return __uint_as_float((unsigned int)h << 16);
}

// ---- async global->LDS, 16B per lane ----
__device__ __forceinline__ void gload16(const unsigned short* g, unsigned short* l) {
  __builtin_amdgcn_global_load_lds(
      (const __attribute__((address_space(1))) unsigned int*)g,
      (__attribute__((address_space(3))) unsigned int*)l, 16, 0, 0);
}

// Fragment-major chunk layout (8 bf16 elems per chunk, 16B):
#define CHUNK(row, kc) ((((row) >> 4) * 8 + (kc)) * 16 + ((row) & 15))

// =================== split: fp32 [R][K] -> bf16 [R][3K] ===================
// mode 0 (A-side): [hi | lo | hi]    mode 1 (B-side): [hi | hi | lo]
__global__ __launch_bounds__(256)
void split3(const float* __restrict__ src, unsigned short* __restrict__ dst,
            int K, int mode) {
  const int r = blockIdx.x;
  const int c = threadIdx.x * 8;
  const float* s = src + (size_t)r * K + c;
  float4 v0 = *(const float4*)s;
  float4 v1 = *(const float4*)(s + 4);
  float v[8] = {v0.x, v0.y, v0.z, v0.w, v1.x, v1.y, v1.z, v1.w};
  unsigned short hi[8], lo[8];
#pragma unroll
  for (int j = 0; j < 8; ++j) {
    hi[j] = f2bf(v[j]);
    lo[j] = f2bf(v[j] - bf2f(hi[j]));
  }
  unsigned short* d = dst + (size_t)r * 3 * K;
  s16x8 hv, lv;
#pragma unroll
  for (int j = 0; j < 8; ++j) { hv[j] = (short)hi[j]; lv[j] = (short)lo[j]; }
  *(s16x8*)(d + c)         = hv;
  *(s16x8*)(d + K + c)     = (mode == 0) ? lv : hv;
  *(s16x8*)(d + 2 * K + c) = (mode == 0) ? hv : lv;
}

// =================== bf16 NT GEMM (m97 structure, unchanged) ===============
#define TBM 128
#define TBN 128
#define TBK 64

__global__ __launch_bounds__(256)
void gemm_bt_bf16(const unsigned short* __restrict__ A2,
                  const unsigned short* __restrict__ B2,
                  float* __restrict__ C, int M, int N, int K2) {
  __shared__ unsigned short As[TBM * TBK];
  __shared__ unsigned short Bs[TBN * TBK];

  const int t  = threadIdx.x;
  const int m0 = blockIdx.y * TBM;
  const int n0 = blockIdx.x * TBN;
  const int w  = t >> 6;
  const int l  = t & 63;
  const int wr = (w >> 1) * 64;
  const int wc = (w & 1) * 64;
  const int srow = t >> 3;
  const int scol = (t & 7) * 8;

  f32x4 acc[4][4];
#pragma unroll
  for (int m = 0; m < 4; ++m)
#pragma unroll
    for (int n = 0; n < 4; ++n)
#pragma unroll
      for (int q = 0; q < 4; ++q) acc[m][n][q] = 0.f;

  const int nsteps = K2 / TBK;
  for (int ks = 0; ks < nsteps; ++ks) {
    const size_t kb = (size_t)ks * TBK;
#pragma unroll
    for (int i = 0; i < 4; ++i) {
      int row = i * 32 + srow;
      gload16(A2 + (size_t)(m0 + row) * K2 + kb + scol, &As[row * TBK + scol]);
      gload16(B2 + (size_t)(n0 + row) * K2 + kb + scol, &Bs[row * TBK + scol]);
    }
    __syncthreads();

#pragma unroll
    for (int kk = 0; kk < 2; ++kk) {
      s16x8 af[4], bf[4];
      const int ko = kk * 32 + (l >> 4) * 8;
#pragma unroll
      for (int m = 0; m < 4; ++m)
        af[m] = *(const s16x8*)&As[(wr + m * 16 + (l & 15)) * TBK + ko];
#pragma unroll
      for (int n = 0; n < 4; ++n)
        bf[n] = *(const s16x8*)&Bs[(wc + n * 16 + (l & 15)) * TBK + ko];
#pragma unroll
      for (int m = 0; m < 4; ++m)
#pragma unroll
        for (int n = 0; n < 4; ++n)
          acc[m][n] = __builtin_amdgcn_mfma_f32_16x16x32_bf16(af[m], bf[n], acc[m][n], 0, 0, 0);
    }
    __syncthreads();
  }

#pragma unroll
  for (int m = 0; m < 4; ++m)
#pragma unroll
    for (int n = 0; n < 4; ++n) {
      int gr = m0 + wr + m * 16 + (l >> 4) * 4;
      int gc = n0 + wc + n * 16 + (l & 15);
#pragma unroll
      for (int j = 0; j < 4; ++j)
        C[(size_t)(gr + j) * N + gc] = acc[m][n][j];
    }
}

// =================== fp32 GEMM fallback ===================
#define GBM 128
#define GBN 128
#define GBK 16
#define GPAD 4

__global__ __launch_bounds__(256)
void gemm_nt(const float* __restrict__ A, const float* __restrict__ Bm,
             float* __restrict__ C, int M, int N, int K) {
  __shared__ float Asf[GBK][GBM + GPAD];
  __shared__ float Bsf[GBK][GBN + GPAD];
  const int t  = threadIdx.x;
  const int m0 = blockIdx.y * GBM;
  const int n0 = blockIdx.x * GBN;
  const int tx = t & 15;
  const int ty = t >> 4;

  float acc[8][8];
#pragma unroll
  for (int i = 0; i < 8; ++i)
#pragma unroll
    for (int j = 0; j < 8; ++j) acc[i][j] = 0.f;

  for (int k0 = 0; k0 < K; k0 += GBK) {
#pragma unroll
    for (int i = 0; i < 2; ++i) {
      int f   = t + i * 256;
      int row = f >> 2;
      int kc  = (f & 3) << 2;
      float4 va = *(const float4*)(A + (size_t)(m0 + row) * K + k0 + kc);
      Asf[kc + 0][row] = va.x; Asf[kc + 1][row] = va.y;
      Asf[kc + 2][row] = va.z; Asf[kc + 3][row] = va.w;
      float4 vb = *(const float4*)(Bm + (size_t)(n0 + row) * K + k0 + kc);
      Bsf[kc + 0][row] = vb.x; Bsf[kc + 1][row] = vb.y;
      Bsf[kc + 2][row] = vb.z; Bsf[kc + 3][row] = vb.w;
    }
    __syncthreads();
#pragma unroll
    for (int kk = 0; kk < GBK; ++kk) {
      float a[8], b[8];
#pragma unroll
      for (int i = 0; i < 8; ++i) a[i] = Asf[kk][ty * 8 + i];
#pragma unroll
      for (int j = 0; j < 8; ++j) b[j] = Bsf[kk][tx * 8 + j];
#pragma unroll
      for (int i = 0; i < 8; ++i)
#pragma unroll
        for (int j = 0; j < 8; ++j) acc[i][j] += a[i] * b[j];
    }
    __syncthreads();
  }
#pragma unroll
  for (int i = 0; i < 8; ++i) {
    float* crow = C + (size_t)(m0 + ty * 8 + i) * N + n0 + tx * 8;
    *(float4*)(crow)     = make_float4(acc[i][0], acc[i][1], acc[i][2], acc[i][3]);
    *(float4*)(crow + 4) = make_float4(acc[i][4], acc[i][5], acc[i][6], acc[i][7]);
  }
}

// ---------------- RoPE cos/sin tables ----------------
__global__ void rope_tables(float* __restrict__ ctab, float* __restrict__ stab) {
  int idx = blockIdx.x * 256 + threadIdx.x;
  if (idx >= L_ * 32) return;
  int l = idx >> 5;
  int i = idx & 31;
  float freq = powf(10000.0f, -(float)(2 * i) / 64.0f);
  float ang  = (float)l * freq;
  ctab[idx] = cosf(ang);
  stab[idx] = sinf(ang);
}

// ---------------- RoPE in place on Q (scaled) and K ----------------
__global__ __launch_bounds__(256)
void rope_inplace(float* __restrict__ qkv, const float* __restrict__ ctab,
                  const float* __restrict__ stab) {
  const int row = blockIdx.x;
  const int l   = row & (L_ - 1);
  float* p = qkv + (size_t)row * OP;
  const int t = threadIdx.x;
#pragma unroll
  for (int k = 0; k < 5; ++k) {
    int item = t + k * 256;
    int hh = item >> 5;
    int d  = item & 31;
    int off = (hh < NH) ? hh * HD + d : KPOS + (hh - NH) * HD + d;
    float sc = (hh < NH) ? SCALE_ : 1.0f;
    float c = ctab[l * 32 + d];
    float s = stab[l * 32 + d];
    float a = p[off];
    float bq = p[off + 32];
    p[off]      = (a * c - bq * s) * sc;
    p[off + 32] = (bq * c + a * s) * sc;
  }
}

// =================== pre-split K and V^T into tiled bf16 hi/lo =============
__global__ __launch_bounds__(256)
void split_kv(const float* __restrict__ qkv, unsigned short* __restrict__ Ksp,
              unsigned short* __restrict__ Vsp) {
  const int kt = blockIdx.x, kvh = blockIdx.y, b = blockIdx.z;
  const int t = threadIdx.x;
  const int srow = t & 63;
  const int pb   = (t >> 6) * 2;
  const size_t tb = (((size_t)(b * NKV + kvh) * 32) + kt) * 8192;
  const float* base = qkv + (size_t)b * L_ * OP;

  // ---- K rows ----
  {
    const float* gk = base + (size_t)(kt * 64 + srow) * OP + KPOS + kvh * HD + pb * 8;
    float kv[16];
#pragma unroll
    for (int i = 0; i < 4; ++i) {
      float4 u = *(const float4*)(gk + 4 * i);
      kv[4 * i] = u.x; kv[4 * i + 1] = u.y; kv[4 * i + 2] = u.z; kv[4 * i + 3] = u.w;
    }
    s16x8 h0, h1, l0, l1;
#pragma unroll
    for (int j = 0; j < 8; ++j) {
      unsigned short hh = f2bf(kv[j]);
      h0[j] = (short)hh; l0[j] = (short)f2bf(kv[j] - bf2f(hh));
      unsigned short h2 = f2bf(kv[j + 8]);
      h1[j] = (short)h2; l1[j] = (short)f2bf(kv[j + 8] - bf2f(h2));
    }
    unsigned short* kd = Ksp + tb;
    *(s16x8*)&kd[CHUNK(srow, pb) * 8]            = h0;
    *(s16x8*)&kd[CHUNK(srow, pb + 1) * 8]        = h1;
    *(s16x8*)&kd[4096 + CHUNK(srow, pb) * 8]     = l0;
    *(s16x8*)&kd[4096 + CHUNK(srow, pb + 1) * 8] = l1;
  }
  // ---- V transposed: thread owns d=srow, k = pb*8 .. pb*8+15 ----
  {
    const float* gv = base + (size_t)(kt * 64 + pb * 8) * OP + VPOS + kvh * HD + srow;
    s16x8 h0, h1, l0, l1;
#pragma unroll
    for (int kk = 0; kk < 8; ++kk) {
      float v0 = gv[(size_t)kk * OP];
      float v1 = gv[(size_t)(kk + 8) * OP];
      unsigned short hh = f2bf(v0);
      h0[kk] = (short)hh; l0[kk] = (short)f2bf(v0 - bf2f(hh));
      unsigned short h2 = f2bf(v1);
      h1[kk] = (short)h2; l1[kk] = (short)f2bf(v1 - bf2f(h2));
    }
    unsigned short* vd = Vsp + tb;
    *(s16x8*)&vd[CHUNK(srow, pb) * 8]            = h0;
    *(s16x8*)&vd[CHUNK(srow, pb + 1) * 8]        = h1;
    *(s16x8*)&vd[4096 + CHUNK(srow, pb) * 8]     = l0;
    *(s16x8*)&vd[4096 + CHUNK(srow, pb + 1) * 8] = l1;
  }
}

// =================== MFMA flash attention v5 ===============================
// QBLK=128, 8 waves (512 thr); wave w owns q rows w*16..w*16+15 of the tile.
// K/V staged once per kt for all 128 q rows (staging/barriers per work halved
// vs v4). Sf is wave-private rows -> no extra barrier. Largest blocks launch
// first (qb reversed); waves fully above the diagonal skip compute.
__global__ __launch_bounds__(512, 2)
void attn_fwd5(const float* __restrict__ qkv,
               const unsigned short* __restrict__ Ksp,
               const unsigned short* __restrict__ Vsp,
               unsigned short* __restrict__ A2out) {
  __shared__ __align__(16) unsigned short Kf[2][4096];   // 16 KB
  __shared__ __align__(16) unsigned short Vf[2][4096];   // 16 KB
  __shared__ __align__(16) unsigned short Sf[2][8192];   // 32 KB (128 rows)

  const int t   = threadIdx.x;
  const int qb  = 15 - blockIdx.x;      // reversed: big blocks first
  const int h   = blockIdx.y;
  const int b   = blockIdx.z;
  const int kvh = h >> 2;
  const int w   = t >> 6;               // wave 0..7
  const int l   = t & 63;
  const int r15 = l & 15;
  const int g   = l >> 4;
  const float* base = qkv + (size_t)b * L_ * OP;

  // ---- Q fragments in registers (RoPE+scale already applied) ----
  s16x8 qhi[2], qlo[2];
  const int qrow = qb * 128 + w * 16 + r15;
  {
    const float* qsrc = base + (size_t)qrow * OP + h * HD + g * 8;
#pragma unroll
    for (int ks = 0; ks < 2; ++ks) {
      float4 a = *(const float4*)(qsrc + ks * 32);
      float4 c = *(const float4*)(qsrc + ks * 32 + 4);
      float v[8] = {a.x, a.y, a.z, a.w, c.x, c.y, c.z, c.w};
#pragma unroll
      for (int j = 0; j < 8; ++j) {
        unsigned short hh = f2bf(v[j]);
        qhi[ks][j] = (short)hh;
        qlo[ks][j] = (short)f2bf(v[j] - bf2f(hh));
      }
    }
  }

  s16x8 onesf;
#pragma unroll
  for (int j = 0; j < 8; ++j) onesf[j] = (short)0x3F80;   // bf16 1.0

  f32x4 acco[4];          // O^T: rows d = m*16+g*4+reg, col q = w*16+r15
  f32x4 acc1;             // ones-row: sum_k P[q][:]
  float m_run[4];
#pragma unroll
  for (int m = 0; m < 4; ++m)
#pragma unroll
    for (int q = 0; q < 4; ++q) acco[m][q] = 0.f;
#pragma unroll
  for (int q = 0; q < 4; ++q) acc1[q] = 0.f;
#pragma unroll
  for (int q = 0; q < 4; ++q) m_run[q] = NEG_BIG;

  const int qmin = qb * 128 + w * 16;         // wave's first q row
  const int qmax = qmin + 15;                 // wave's last q row
  const int ktmax = 2 * qb + 1;

  for (int kt = 0; kt <= ktmax; ++kt) {
    // ---- async staging: pre-split tile image -> LDS (4 issues, 512 thr) ----
    const size_t tb = (((size_t)(b * NKV + kvh) * 32) + kt) * 8192;
    const unsigned short* kt_k = Ksp + tb;
    const unsigned short* kt_v = Vsp + tb;
#pragma unroll
    for (int p = 0; p < 2; ++p) {
      const int e = t * 8;
      gload16(kt_k + p * 4096 + e, &Kf[p][e]);
      gload16(kt_v + p * 4096 + e, &Vf[p][e]);
    }
    __syncthreads();   // drains vmcnt

    const bool active = (kt * 64 <= qmax);    // wave has unmasked cols
    if (active) {
      // ---- S = Q K^T ----
      f32x4 accs[4];
#pragma unroll
      for (int n = 0; n < 4; ++n)
#pragma unroll
        for (int q = 0; q < 4; ++q) accs[n][q] = 0.f;

#pragma unroll
      for (int ks = 0; ks < 2; ++ks) {
        const int kc = ks * 4 + g;
#pragma unroll
        for (int n = 0; n < 4; ++n) {
          s16x8 bh = *(const s16x8*)&Kf[0][CHUNK(n * 16 + r15, kc) * 8];
          s16x8 bl = *(const s16x8*)&Kf[1][CHUNK(n * 16 + r15, kc) * 8];
          accs[n] = __builtin_amdgcn_mfma_f32_16x16x32_bf16(qhi[ks], bh, accs[n], 0, 0, 0);
          accs[n] = __builtin_amdgcn_mfma_f32_16x16x32_bf16(qlo[ks], bh, accs[n], 0, 0, 0);
          accs[n] = __builtin_amdgcn_mfma_f32_16x16x32_bf16(qhi[ks], bl, accs[n], 0, 0, 0);
        }
      }

      // ---- causal mask (only on waves straddling the diagonal) ----
      if (kt * 64 + 63 > qmin) {
#pragma unroll
        for (int n = 0; n < 4; ++n) {
          int col = kt * 64 + n * 16 + r15;
#pragma unroll
          for (int q = 0; q < 4; ++q) {
            int row = qmin + g * 4 + q;
            if (col > row) accs[n][q] = NEG_BIG;
          }
        }
      }

      // ---- online max + exp (S-layout); sums via ones-MFMA ----
      float alpha[4];
#pragma unroll
      for (int q = 0; q < 4; ++q) {
        float mx = fmaxf(fmaxf(accs[0][q], accs[1][q]), fmaxf(accs[2][q], accs[3][q]));
        mx = fmaxf(mx, __shfl_xor(mx, 1));
        mx = fmaxf(mx, __shfl_xor(mx, 2));
        mx = fmaxf(mx, __shfl_xor(mx, 4));
        mx = fmaxf(mx, __shfl_xor(mx, 8));
        float mnew = fmaxf(m_run[q], mx);
        alpha[q] = __expf(m_run[q] - mnew);
        m_run[q] = mnew;
#pragma unroll
        for (int n = 0; n < 4; ++n) accs[n][q] = __expf(accs[n][q] - mnew);
      }

      // ---- write P (hi/lo) to Sf (wave-private rows) ----
#pragma unroll
      for (int n = 0; n < 4; ++n) {
        const int kc = n * 2 + (r15 >> 3);
#pragma unroll
        for (int q = 0; q < 4; ++q) {
          int e = CHUNK(w * 16 + g * 4 + q, kc) * 8 + (l & 7);
          float p = accs[n][q];
          unsigned short hh = f2bf(p);
          Sf[0][e] = hh;
          Sf[1][e] = f2bf(p - bf2f(hh));
        }
      }

      // ---- rescale O^T (and ones-acc) by alpha routed to O-layout ----
      {
        int src = (r15 >> 2) << 4;
        float a0 = __shfl(alpha[0], src);
        float a1 = __shfl(alpha[1], src);
        float a2 = __shfl(alpha[2], src);
        float a3 = __shfl(alpha[3], src);
        int sel = r15 & 3;
        float aq = (sel == 0) ? a0 : (sel == 1) ? a1 : (sel == 2) ? a2 : a3;
#pragma unroll
        for (int m = 0; m < 4; ++m)
#pragma unroll
          for (int q = 0; q < 4; ++q) acco[m][q] *= aq;
#pragma unroll
        for (int q = 0; q < 4; ++q) acc1[q] *= aq;
      }

      // ---- O^T += V^T P^T ; ones-row accumulates sum(P) ----
#pragma unroll
      for (int ks = 0; ks < 2; ++ks) {
        const int kc = ks * 4 + g;
        s16x8 bh = *(const s16x8*)&Sf[0][CHUNK(w * 16 + r15, kc) * 8];
        s16x8 bl = *(const s16x8*)&Sf[1][CHUNK(w * 16 + r15, kc) * 8];
        acc1 = __builtin_amdgcn_mfma_f32_16x16x32_bf16(onesf, bh, acc1, 0, 0, 0);
        acc1 = __builtin_amdgcn_mfma_f32_16x16x32_bf16(onesf, bl, acc1, 0, 0, 0);
#pragma unroll
        for (int m = 0; m < 4; ++m) {
          s16x8 ah = *(const s16x8*)&Vf[0][CHUNK(m * 16 + r15, kc) * 8];
          s16x8 al = *(const s16x8*)&Vf[1][CHUNK(m * 16 + r15, kc) * 8];
          acco[m] = __builtin_amdgcn_mfma_f32_16x16x32_bf16(ah, bh, acco[m], 0, 0, 0);
          acco[m] = __builtin_amdgcn_mfma_f32_16x16x32_bf16(al, bh, acco[m], 0, 0, 0);
          acco[m] = __builtin_amdgcn_mfma_f32_16x16x32_bf16(ah, bl, acco[m], 0, 0, 0);
        }
      }
    }
    __syncthreads();   // protect Kf/Vf before next staging
  }

  // ---- normalize + store split-bf16 directly into A2 [hi|lo|hi] ----
  {
    float invq = 1.f / acc1[0];
    unsigned short* arow = A2out + (size_t)(b * L_ + qrow) * (3 * QPOS) + h * HD + g * 4;
#pragma unroll
    for (int m = 0; m < 4; ++m) {
      s16x4 hv, lv;
#pragma unroll
      for (int j = 0; j < 4; ++j) {
        float v = acco[m][j] * invq;
        unsigned short hh = f2bf(v);
        hv[j] = (short)hh;
        lv[j] = (short)f2bf(v - bf2f(hh));
      }
      *(s16x4*)(arow + m * 16)            = hv;
      *(s16x4*)(arow + QPOS + m * 16)     = lv;
      *(s16x4*)(arow + 2 * QPOS + m * 16) = hv;
    }
  }
}

// ---------------- fp32 flash attention fallback (round-2 version) ----------
#define LDA 68

__global__ __launch_bounds__(256)
void attn_fwd2(const float* __restrict__ qkv, float* __restrict__ out) {
  __shared__ float QsT[HD][LDA];
  __shared__ float KsT[HD][LDA];
  __shared__ float Vs[64][LDA];
  __shared__ float SsT[64][LDA];

  const int t   = threadIdx.x;
  const int qt  = blockIdx.x;
  const int h   = blockIdx.y;
  const int b   = blockIdx.z;
  const int kvh = h >> 2;
  const int tx  = t & 15;
  const int ty  = t >> 4;
  const int r   = t >> 2;
  const int seg = t & 3;
  const float* base = qkv + (size_t)b * L_ * OP;

  {
    const float* src = base + (size_t)(qt * 64 + r) * OP + h * HD + seg * 16;
#pragma unroll
    for (int u = 0; u < 4; ++u) {
      float4 v = *(const float4*)(src + 4 * u);
      int d = seg * 16 + 4 * u;
      QsT[d + 0][r] = v.x; QsT[d + 1][r] = v.y;
      QsT[d + 2][r] = v.z; QsT[d + 3][r] = v.w;
    }
  }

  float m_run[4], l_run[4], o[4][4];
#pragma unroll
  for (int i = 0; i < 4; ++i) {
    m_run[i] = NEG_BIG; l_run[i] = 0.f;
#pragma unroll
    for (int j = 0; j < 4; ++j) o[i][j] = 0.f;
  }

  for (int kt = 0; kt <= qt; ++kt) {
    {
      const float* ksrc = base + (size_t)(kt * 64 + r) * OP + KPOS + kvh * HD + seg * 16;
      const float* vsrc = base + (size_t)(kt * 64 + r) * OP + VPOS + kvh * HD + seg * 16;
#pragma unroll
      for (int u = 0; u < 4; ++u) {
        float4 kv = *(const float4*)(ksrc + 4 * u);
        int d = seg * 16 + 4 * u;
        KsT[d + 0][r] = kv.x; KsT[d + 1][r] = kv.y;
        KsT[d + 2][r] = kv.z; KsT[d + 3][r] = kv.w;
        *(float4*)&Vs[r][seg * 16 + 4 * u] = *(const float4*)(vsrc + 4 * u);
      }
    }
    __syncthreads();

    float s4[4][4];
#pragma unroll
    for (int i = 0; i < 4; ++i)
#pragma unroll
      for (int j = 0; j < 4; ++j) s4[i][j] = 0.f;

#pragma unroll 4
    for (int d = 0; d < 64; ++d) {
      float4 qa = *(const float4*)&QsT[d][ty * 4];
      float4 kb = *(const float4*)&KsT[d][tx * 4];
      float a[4] = {qa.x, qa.y, qa.z, qa.w};
      float bb[4] = {kb.x, kb.y, kb.z, kb.w};
#pragma unroll
      for (int i = 0; i < 4; ++i)
#pragma unroll
        for (int j = 0; j < 4; ++j) s4[i][j] += a[i] * bb[j];
    }

    if (kt == qt) {
#pragma unroll
      for (int i = 0; i < 4; ++i)
#pragma unroll
        for (int j = 0; j < 4; ++j)
          if (tx * 4 + j > ty * 4 + i) s4[i][j] = NEG_BIG;
    }

#pragma unroll
    for (int i = 0; i < 4; ++i) {
      float mloc = fmaxf(fmaxf(s4[i][0], s4[i][1]), fmaxf(s4[i][2], s4[i][3]));
      mloc = fmaxf(mloc, __shfl_xor(mloc, 1));
      mloc = fmaxf(mloc, __shfl_xor(mloc, 2));
      mloc = fmaxf(mloc, __shfl_xor(mloc, 4));
      mloc = fmaxf(mloc, __shfl_xor(mloc, 8));
      float mnew  = fmaxf(m_run[i], mloc);
      float alpha = __expf(m_run[i] - mnew);
      float psum  = 0.f;
#pragma unroll
      for (int j = 0; j < 4; ++j) {
        float pv = __expf(s4[i][j] - mnew);
        s4[i][j] = pv;
        psum += pv;
      }
      psum += __shfl_xor(psum, 1);
      psum += __shfl_xor(psum, 2);
      psum += __shfl_xor(psum, 4);
      psum += __shfl_xor(psum, 8);
      l_run[i] = l_run[i] * alpha + psum;
      m_run[i] = mnew;
#pragma unroll
      for (int j = 0; j < 4; ++j) o[i][j] *= alpha;
    }

#pragma unroll
    for (int j = 0; j < 4; ++j)
#pragma unroll
      for (int i = 0; i < 4; ++i)
        SsT[tx * 4 + j][ty * 4 + i] = s4[i][j];
    __syncthreads();

#pragma unroll 4
    for (int k = 0; k < 64; ++k) {
      float4 pa = *(const float4*)&SsT[k][ty * 4];
      float4 vb = *(const float4*)&Vs[k][tx * 4];
      float a[4] = {pa.x, pa.y, pa.z, pa.w};
      float bb[4] = {vb.x, vb.y, vb.z, vb.w};
#pragma unroll
      for (int i = 0; i < 4; ++i)
#pragma unroll
        for (int j = 0; j < 4; ++j) o[i][j] += a[i] * bb[j];
    }
    __syncthreads();
  }

#pragma unroll
  for (int i = 0; i < 4; ++i) {
    float inv = 1.f / l_run[i];
    float* dst = out + ((size_t)(b * L_ + qt * 64 + ty * 4 + i)) * QPOS + h * HD + tx * 4;
    *(float4*)dst = make_float4(o[i][0] * inv, o[i][1] * inv,
                                o[i][2] * inv, o[i][3] * inv);
  }
}

// ---------------- launch ----------------
extern "C" void kernel_launch(void* const* d_in, const int* in_sizes, int n_in,
                              void* d_out, int out_size, void* d_ws, size_t ws_size,
                              hipStream_t stream) {
  const float* x    = (const float*)d_in[0];   // [B,L,D]
  const float* Wqkv = (const float*)d_in[1];   // [OP,D]
  const float* Wo   = (const float*)d_in[2];   // [D, NH*HD]
  float* outp = (float*)d_out;
  float* ws   = (float*)d_ws;

  float* qkv_ws  = ws;                                   // 12.58M f32
  float* attn_ws = qkv_ws + (size_t)(B_ * L_) * OP;      //  8.39M f32 (fallback only)
  float* ctab    = attn_ws + (size_t)(B_ * L_) * QPOS;
  float* stab    = ctab + (size_t)L_ * 32;
  unsigned short* A2 = (unsigned short*)(stab + (size_t)L_ * 32);
  unsigned short* B2 = A2 + (size_t)4096 * 6144;

  // In the MFMA path attn_ws is unused -> alias the pre-split K/V tiles there.
  unsigned short* Ksp = (unsigned short*)attn_ws;        // 8MB
  unsigned short* Vsp = Ksp + (size_t)B_ * NKV * 32 * 8192;

  const size_t NEED = ((size_t)21102592) * 4 + ((size_t)44040192) * 2;  // 172.5MB
  const bool mfma_ok = ws_size >= NEED;

  if (mfma_ok) {
    // 1) QKV projection via split-bf16 MFMA
    split3<<<dim3(B_ * L_), 256, 0, stream>>>(x, A2, D_, 0);
    split3<<<dim3(OP), 256, 0, stream>>>(Wqkv, B2, D_, 1);
    gemm_bt_bf16<<<dim3(OP / TBN, (B_ * L_) / TBM), 256, 0, stream>>>(
        A2, B2, qkv_ws, B_ * L_, OP, 3 * D_);

    // 2) RoPE
    rope_tables<<<dim3((L_ * 32 + 255) / 256), 256, 0, stream>>>(ctab, stab);
    rope_inplace<<<dim3(B_ * L_), 256, 0, stream>>>(qkv_ws, ctab, stab);

    // 3) pre-split K/V tiles, then MFMA attention -> writes A2 directly
    split_kv<<<dim3(32, NKV, B_), 256, 0, stream>>>(qkv_ws, Ksp, Vsp);
    attn_fwd5<<<dim3(L_ / 128, NH, B_), 512, 0, stream>>>(qkv_ws, Ksp, Vsp, A2);

    // 4) output projection
    split3<<<dim3(D_), 256, 0, stream>>>(Wo, B2, QPOS, 1);
    gemm_bt_bf16<<<dim3(D_ / TBN, (B_ * L_) / TBM), 256, 0, stream>>>(
        A2, B2, outp, B_ * L_, D_, 3 * QPOS);
  } else {
    gemm_nt<<<dim3(OP / GBN, (B_ * L_) / GBM), 256, 0, stream>>>(
        x, Wqkv, qkv_ws, B_ * L_, OP, D_);
    rope_tables<<<dim3((L_ * 32 + 255) / 256), 256, 0, stream>>>(ctab, stab);
    rope_inplace<<<dim3(B_ * L_), 256, 0, stream>>>(qkv_ws, ctab, stab);
    attn_fwd2<<<dim3(L_ / 64, NH, B_), 256, 0, stream>>>(qkv_ws, attn_ws);
    gemm_nt<<<dim3(D_ / GBN, (B_ * L_) / GBM), 256, 0, stream>>>(
        attn_ws, Wo, outp, B_ * L_, D_, QPOS);
  }
}